// Round 18
// baseline (429.822 us; speedup 1.0000x reference)
//
#include <hip/hip_runtime.h>
#include <hip/hip_bf16.h>

#define NN   100000
#define HIDD 128
#define NBC  196          // ceil(NN/512) coarse buckets of 512 nodes

typedef __attribute__((ext_vector_type(8))) short bf16x8;
typedef __attribute__((ext_vector_type(2))) float f32x2;
typedef __attribute__((ext_vector_type(4))) float f32x4;
typedef __attribute__((ext_vector_type(16))) float f32x16;

// RNE fp32 -> bf16 bits
__device__ __forceinline__ short bf16_rne(float v) {
    unsigned u = __float_as_uint(v);
    unsigned r = (u + 0x7fffu + ((u >> 16) & 1u)) >> 16;
    return (short)r;
}
__device__ __forceinline__ float bf16_to_f32(short b) {
    return __uint_as_float(((unsigned)(unsigned short)b) << 16);
}
__device__ __forceinline__ float bf16u_to_f32(ushort b) {
    return __uint_as_float(((unsigned)b) << 16);
}
__device__ __forceinline__ f32x2 unpack2p(unsigned u) {
    f32x2 r;
    r[0] = __uint_as_float((u & 0xFFFFu) << 16);
    r[1] = __uint_as_float(u & 0xFFFF0000u);
    return r;
}
__device__ __forceinline__ unsigned pack2(float a, float b) {
    return ((unsigned)(unsigned short)bf16_rne(a)) |
           (((unsigned)(unsigned short)bf16_rne(b)) << 16);
}

// ---------------------------------------------------------------------------
// Bucketed CSR build. bucket = dst >> 9 (512 nodes per bucket).
// ---------------------------------------------------------------------------
__global__ __launch_bounds__(256)
void bucket_hist(const int* __restrict__ edges, int n_edges,
                 int* __restrict__ bcnt) {
    __shared__ int lh[NBC];
    for (int i = threadIdx.x; i < NBC; i += 256) lh[i] = 0;
    __syncthreads();
    int stride = gridDim.x * blockDim.x;
    for (int e = blockIdx.x * blockDim.x + threadIdx.x; e < n_edges; e += stride) {
        int d = edges[n_edges + e];
        if ((unsigned)d < NN) atomicAdd(&lh[d >> 9], 1);
    }
    __syncthreads();
    for (int i = threadIdx.x; i < NBC; i += 256)
        if (lh[i]) atomicAdd(&bcnt[i], lh[i]);
}

__global__ void scan_bptr(const int* __restrict__ bcnt, int* __restrict__ bptr) {
    __shared__ int lds[256];
    int t = threadIdx.x;
    lds[t] = (t < NBC) ? bcnt[t] : 0;
    __syncthreads();
    for (int off = 1; off < 256; off <<= 1) {
        int u = (t >= off) ? lds[t - off] : 0;
        __syncthreads();
        lds[t] += u;
        __syncthreads();
    }
    if (t < NBC) bptr[t + 1] = lds[t];
    if (t == 0) bptr[0] = 0;
}

// Scatter edges into bucket regions as packed (dst_local<<17 | src).
#define SCAT_CHUNK 4096
__global__ __launch_bounds__(256)
void bucket_scatter(const int* __restrict__ edges, int n_edges,
                    const int* __restrict__ bptr, int* __restrict__ bcur,
                    int* __restrict__ bedges) {
    __shared__ int lh[NBC];
    __shared__ int lbase[NBC];
    int t = threadIdx.x;
    int base = blockIdx.x * SCAT_CHUNK;
    for (int i = t; i < NBC; i += 256) lh[i] = 0;
    __syncthreads();
#pragma unroll
    for (int i = 0; i < SCAT_CHUNK / 256; ++i) {
        int e = base + i * 256 + t;
        if (e < n_edges) {
            int d = edges[n_edges + e];
            if ((unsigned)d < NN) atomicAdd(&lh[d >> 9], 1);
        }
    }
    __syncthreads();
    for (int i = t; i < NBC; i += 256) {
        int c = lh[i];
        lbase[i] = (c > 0) ? atomicAdd(&bcur[i], c) : 0;
        lh[i] = 0;   // reuse as cursor
    }
    __syncthreads();
#pragma unroll
    for (int i = 0; i < SCAT_CHUNK / 256; ++i) {
        int e = base + i * 256 + t;
        if (e < n_edges) {
            int s = edges[e];
            int d = edges[n_edges + e];
            if ((unsigned)d < NN && (unsigned)s < NN) {
                int b = d >> 9;
                int off = atomicAdd(&lh[b], 1);
                bedges[bptr[b] + lbase[b] + off] = ((d & 511) << 17) | s;
            }
        }
    }
}

// One block per 512-node bucket: count -> pairwise scan -> place.
__global__ __launch_bounds__(256)
void bucket_csr512(const int* __restrict__ bedges, const int* __restrict__ bptr,
                   int* __restrict__ row_ptr, int* __restrict__ col_src) {
    __shared__ int lcnt[512];
    __shared__ int lsum[256];
    __shared__ int lexcl[512];
    int b = blockIdx.x;
    int t = threadIdx.x;
    int beg = bptr[b], end = bptr[b + 1];
    lcnt[t] = 0; lcnt[t + 256] = 0;
    __syncthreads();
    for (int e = beg + t; e < end; e += 256)
        atomicAdd(&lcnt[bedges[e] >> 17], 1);
    __syncthreads();
    int a0 = lcnt[2 * t], a1 = lcnt[2 * t + 1];
    lsum[t] = a0 + a1;
    __syncthreads();
    for (int off = 1; off < 256; off <<= 1) {
        int u = (t >= off) ? lsum[t - off] : 0;
        __syncthreads();
        lsum[t] += u;
        __syncthreads();
    }
    int pairExcl = lsum[t] - (a0 + a1);     // exclusive prefix of element 2t
    lexcl[2 * t]     = pairExcl;
    lexcl[2 * t + 1] = pairExcl + a0;
    int node0 = b << 9;
    int n0 = node0 + 2 * t, n1 = node0 + 2 * t + 1;
    if (n0 < NN) row_ptr[n0] = beg + pairExcl;
    if (n1 < NN) row_ptr[n1] = beg + pairExcl + a0;
    lcnt[2 * t] = 0; lcnt[2 * t + 1] = 0;   // reuse as cursors
    if (b == NBC - 1 && t == 0) row_ptr[NN] = end;
    __syncthreads();
    for (int e = beg + t; e < end; e += 256) {
        int p = bedges[e];
        int dl = p >> 17, src = p & 0x1FFFF;
        int pos = atomicAdd(&lcnt[dl], 1);
        col_src[beg + lexcl[dl] + pos] = src;
    }
}

// ---------------------------------------------------------------------------
// fp32 -> bf16 conversion (x)
// ---------------------------------------------------------------------------
__global__ void to_bf16(const float* __restrict__ in, ushort* __restrict__ out, int n) {
    int i = (blockIdx.x * blockDim.x + threadIdx.x) * 4;
    if (i + 3 >= n) {
        for (int k = i; k < n; ++k) out[k] = (ushort)bf16_rne(in[k]);
        return;
    }
    float4 v = *(const float4*)&in[i];
    unsigned lo = pack2(v.x, v.y), hi = pack2(v.z, v.w);
    *(uint2*)&out[i] = make_uint2(lo, hi);
}

// ---------------------------------------------------------------------------
// fp8 pull-mode mean aggregation: one wave per node, row = 128B.
// ---------------------------------------------------------------------------
__device__ __forceinline__ void acc_fp8x8p(f32x2* s, uint2 u) {
    s[0] += __builtin_amdgcn_cvt_pk_f32_fp8(u.x, false);
    s[1] += __builtin_amdgcn_cvt_pk_f32_fp8(u.x, true);
    s[2] += __builtin_amdgcn_cvt_pk_f32_fp8(u.y, false);
    s[3] += __builtin_amdgcn_cvt_pk_f32_fp8(u.y, true);
}

__global__ void aggregate128_fp8(const unsigned char* __restrict__ h8,
                                 const int* __restrict__ row_ptr,
                                 const int* __restrict__ col_src,
                                 ushort* __restrict__ aggr16, int n_nodes) {
    int node = (int)((blockIdx.x * (size_t)blockDim.x + threadIdx.x) >> 6);
    int lane = threadIdx.x & 63;
    if (node >= n_nodes) return;
    const int g   = lane >> 4;        // neighbor group 0..3
    const int seg = lane & 15;        // 8B segment within 128B row
    int beg = row_ptr[node], end = row_ptr[node + 1];
    f32x2 s[4];
#pragma unroll
    for (int e = 0; e < 4; ++e) s[e] = (f32x2){0.f, 0.f};
    int j = beg;
    for (; j + 16 <= end; j += 16) {               // 4 batches in flight
        int i0 = col_src[j + g];
        int i1 = col_src[j + 4 + g];
        int i2 = col_src[j + 8 + g];
        int i3 = col_src[j + 12 + g];
        uint2 u0 = *(const uint2*)&h8[(size_t)i0 * HIDD + seg * 8];
        uint2 u1 = *(const uint2*)&h8[(size_t)i1 * HIDD + seg * 8];
        uint2 u2 = *(const uint2*)&h8[(size_t)i2 * HIDD + seg * 8];
        uint2 u3 = *(const uint2*)&h8[(size_t)i3 * HIDD + seg * 8];
        acc_fp8x8p(s, u0);
        acc_fp8x8p(s, u1);
        acc_fp8x8p(s, u2);
        acc_fp8x8p(s, u3);
    }
    for (; j + 8 <= end; j += 8) {                 // 2 batches in flight
        int i0 = col_src[j + g];
        int i1 = col_src[j + 4 + g];
        uint2 u0 = *(const uint2*)&h8[(size_t)i0 * HIDD + seg * 8];
        uint2 u1 = *(const uint2*)&h8[(size_t)i1 * HIDD + seg * 8];
        acc_fp8x8p(s, u0);
        acc_fp8x8p(s, u1);
    }
    for (; j + 4 <= end; j += 4) {
        int i0 = col_src[j + g];
        uint2 u0 = *(const uint2*)&h8[(size_t)i0 * HIDD + seg * 8];
        acc_fp8x8p(s, u0);
    }
    int rem = end - j;
    if (g < rem) {                                 // masked tail, one step
        int i0 = col_src[j + g];
        uint2 u0 = *(const uint2*)&h8[(size_t)i0 * HIDD + seg * 8];
        acc_fp8x8p(s, u0);
    }
    // reduce across the 4 groups
#pragma unroll
    for (int e = 0; e < 4; ++e) {
        s[e][0] += __shfl_xor(s[e][0], 16);
        s[e][1] += __shfl_xor(s[e][1], 16);
        s[e][0] += __shfl_xor(s[e][0], 32);
        s[e][1] += __shfl_xor(s[e][1], 32);
    }
    float inv = (end > beg) ? 1.0f / (float)(end - beg) : 0.0f;
    if (lane < 16) {
        unsigned r0 = pack2(s[0][0] * inv, s[0][1] * inv);
        unsigned r1 = pack2(s[1][0] * inv, s[1][1] * inv);
        unsigned r2 = pack2(s[2][0] * inv, s[2][1] * inv);
        unsigned r3 = pack2(s[3][0] * inv, s[3][1] * inv);
        *(uint4*)&aggr16[(size_t)node * HIDD + seg * 8] = make_uint4(r0, r1, r2, r3);
    }
}

// One wave per node; 4 lanes x 16B cover one 64B row; 16 groups =>
// 16 neighbors per load instruction. Packed f32x2 accumulation.
__global__ void aggregate32_bf16(const ushort* __restrict__ x16,
                                 const int* __restrict__ row_ptr,
                                 const int* __restrict__ col_src,
                                 ushort* __restrict__ aggr16, int n_nodes) {
    int node = (int)((blockIdx.x * (size_t)blockDim.x + threadIdx.x) >> 6);
    int lane = threadIdx.x & 63;
    if (node >= n_nodes) return;
    const int g   = lane >> 2;        // neighbor group 0..15
    const int seg = lane & 3;         // 16B segment within 64B row
    int beg = row_ptr[node], end = row_ptr[node + 1];
    f32x2 s[4];
#pragma unroll
    for (int e = 0; e < 4; ++e) s[e] = (f32x2){0.f, 0.f};
    int j = beg;
    for (; j + 16 <= end; j += 16) {
        int i0 = col_src[j + g];
        uint4 u = *(const uint4*)&x16[(size_t)i0 * 32 + seg * 8];
        s[0] += unpack2p(u.x);
        s[1] += unpack2p(u.y);
        s[2] += unpack2p(u.z);
        s[3] += unpack2p(u.w);
    }
    int rem = end - j;
    if (g < rem) {                                 // masked tail (up to 15)
        int i0 = col_src[j + g];
        uint4 u = *(const uint4*)&x16[(size_t)i0 * 32 + seg * 8];
        s[0] += unpack2p(u.x);
        s[1] += unpack2p(u.y);
        s[2] += unpack2p(u.z);
        s[3] += unpack2p(u.w);
    }
    // reduce across the 16 groups
#pragma unroll
    for (int e = 0; e < 4; ++e) {
#pragma unroll
        for (int h = 0; h < 2; ++h) {
            s[e][h] += __shfl_xor(s[e][h], 4);
            s[e][h] += __shfl_xor(s[e][h], 8);
            s[e][h] += __shfl_xor(s[e][h], 16);
            s[e][h] += __shfl_xor(s[e][h], 32);
        }
    }
    float inv = (end > beg) ? 1.0f / (float)(end - beg) : 0.0f;
    if (lane < 4) {
        unsigned r0 = pack2(s[0][0] * inv, s[0][1] * inv);
        unsigned r1 = pack2(s[1][0] * inv, s[1][1] * inv);
        unsigned r2 = pack2(s[2][0] * inv, s[2][1] * inv);
        unsigned r3 = pack2(s[3][0] * inv, s[3][1] * inv);
        *(uint4*)&aggr16[(size_t)node * 32 + seg * 8] = make_uint4(r0, r1, r2, r3);
    }
}

// ---------------------------------------------------------------------------
// Weight pre-split: fp32 -> (hi, lo) bf16 planes, all 6 conv matrices.
// ---------------------------------------------------------------------------
__global__ void split_weights(const float* __restrict__ W1l, const float* __restrict__ W1r,
                              const float* __restrict__ W2l, const float* __restrict__ W2r,
                              const float* __restrict__ W3l, const float* __restrict__ W3r,
                              short* __restrict__ whi, short* __restrict__ wlo) {
    int i = blockIdx.x * blockDim.x + threadIdx.x;
    if (i >= 73728) return;
    const float* src; int off;
    if (i < 4096)       { src = W1l; off = 0; }
    else if (i < 8192)  { src = W1r; off = 4096; }
    else if (i < 24576) { src = W2l; off = 8192; }
    else if (i < 40960) { src = W2r; off = 24576; }
    else if (i < 57344) { src = W3l; off = 40960; }
    else                { src = W3r; off = 57344; }
    float v = src[i - off];
    short h = bf16_rne(v);
    float l = v - bf16_to_f32(h);
    whi[i] = h;
    wlo[i] = bf16_rne(l);
}

// ---------------------------------------------------------------------------
// 32x32x16-MFMA dual GEMM — v3 (occupancy-first):
// Block = 4 waves owns ONE 32-col strip (strip = blockIdx&3) -> W-stage is
// 32KB LDS (2op x 8ch x 2pl x 1KB) -> 5 blocks/CU (r17: 64KB + 136 VGPR gave
// 9% occupancy; latency-exposed). Single acc chain, no prefetch (r13 loop,
// ~52 VGPR; launch_bounds(256,5) caps at 102). Each wave = one 32-row subtile
// -> 128-row block tiles; 782 tiles; grid 4x391 (2 tiles/block).
// A rows read by 4 strip-blocks; extra reads hit L3 (aggr+h fits).
// FP8OUT: epilogue also emits fp8 e4m3 copy for the next layer's gather.
// ---------------------------------------------------------------------------
template <int KA, bool RELU, bool MEAN, bool FP8OUT>
__global__ __launch_bounds__(256, 5)
void gemm32(const ushort* __restrict__ inA, const ushort* __restrict__ inB,
            const short* __restrict__ WAhi, const short* __restrict__ WAlo,
            const short* __restrict__ WBhi, const short* __restrict__ WBlo,
            const float* __restrict__ bias,
            ushort* __restrict__ out, unsigned char* __restrict__ out8,
            float* __restrict__ gsum) {
    constexpr int NCH = KA / 16;            // k-chunks of 16
    constexpr int NT  = (NN + 127) / 128;   // 782 tiles of 128 rows
    __shared__ __align__(16) ushort sW[512 * 4 * NCH];  // 32KB at KA=128

    const int t = threadIdx.x;
    const int wave = t >> 6, lane = t & 63;
    const int strip = blockIdx.x & 3;       // 32-col strip
    const int col = lane & 31;
    const int kh  = lane >> 5;              // k-half of the fragment
    const int o0 = strip * 32;

    // ---- stage W (hi+lo, both ops) for this strip; frag-linear layout ----
    // frag f = (op*NCH+ch)*2+pl, 512 ushorts each: offset (kh*32+col)*8
    for (int i = t; i < 256 * NCH; i += 256) {
        int f = i >> 6;
        int w = i & 63;
        int wkh = w >> 5, wcol = w & 31;
        int op = f / (NCH * 2);
        int r2 = f % (NCH * 2);
        int ch = r2 >> 1, pl = r2 & 1;
        const short* Wp = op ? (pl ? WBlo : WBhi) : (pl ? WAlo : WAhi);
        bf16x8 v = *(const bf16x8*)&Wp[(size_t)(o0 + wcol) * KA + ch * 16 + wkh * 8];
        *(bf16x8*)&sW[(size_t)i * 8] = v;
    }
    __syncthreads();

    const int sbase = kh * 256 + col * 8;
    const float bv = MEAN ? 0.f : bias[o0 + col];
    float csum = 0.f;
    const int step = gridDim.x >> 2;

    for (int rt = blockIdx.x >> 2; rt < NT; rt += step) {
        const int r0 = rt * 128 + wave * 32;
        const int ar = min(r0 + col, NN - 1);     // clamped load row
        f32x16 acc = {0.f,0.f,0.f,0.f,0.f,0.f,0.f,0.f,
                      0.f,0.f,0.f,0.f,0.f,0.f,0.f,0.f};
#pragma unroll
        for (int op = 0; op < 2; ++op) {
            const ushort* __restrict__ in = op ? inB : inA;
            const ushort* ab = in + (size_t)ar * KA + kh * 8;
            bf16x8 a[NCH];
#pragma unroll
            for (int ch = 0; ch < NCH; ++ch) a[ch] = *(const bf16x8*)(ab + ch * 16);
#pragma unroll
            for (int ch = 0; ch < NCH; ++ch) {
                bf16x8 wh = *(const bf16x8*)&sW[sbase + ((op * NCH + ch) * 2 + 0) * 512];
                acc = __builtin_amdgcn_mfma_f32_32x32x16_bf16(a[ch], wh, acc, 0, 0, 0);
                bf16x8 wl = *(const bf16x8*)&sW[sbase + ((op * NCH + ch) * 2 + 1) * 512];
                acc = __builtin_amdgcn_mfma_f32_32x32x16_bf16(a[ch], wl, acc, 0, 0, 0);
            }
        }
        if (r0 < NN) {                      // whole 32-row subtile valid or not
            if (!MEAN) {
                const int o = o0 + col;
                const int rb = r0 + 4 * kh;
#pragma unroll
                for (int reg = 0; reg < 16; reg += 2) {
                    int ra = rb + (reg & 3) + 8 * (reg >> 2);   // pair rows ra, ra+1
                    float v0 = acc[reg] + bv;
                    float v1 = acc[reg + 1] + bv;
                    if (RELU) { v0 = fmaxf(v0, 0.f); v1 = fmaxf(v1, 0.f); }
                    out[(size_t)ra * HIDD + o]       = (ushort)bf16_rne(v0);
                    out[(size_t)(ra + 1) * HIDD + o] = (ushort)bf16_rne(v1);
                    if (FP8OUT) {
                        unsigned w = __builtin_amdgcn_cvt_pk_fp8_f32(v0, v1, 0u, false);
                        out8[(size_t)ra * HIDD + o]       = (unsigned char)(w & 0xFF);
                        out8[(size_t)(ra + 1) * HIDD + o] = (unsigned char)((w >> 8) & 0xFF);
                    }
                }
            } else {
#pragma unroll
                for (int reg = 0; reg < 16; ++reg) csum += acc[reg];
            }
        }
    }

    if (MEAN) {
        csum += __shfl_xor(csum, 32);       // combine the two k-half row-subsets
        if (lane < 32) atomicAdd(&gsum[o0 + col], csum);
    }
}

// ---------------------------------------------------------------------------
// Heads: g = gsum/N + b3; logits = relu(g@Pw1.T+Pb1)@Pw2.T+Pb2; value likewise.
// ---------------------------------------------------------------------------
__global__ void heads_kernel(const float* __restrict__ gsum,
                             const float* __restrict__ b3,
                             const float* __restrict__ Pw1, const float* __restrict__ Pb1,
                             const float* __restrict__ Pw2, const float* __restrict__ Pb2,
                             const float* __restrict__ Vw1, const float* __restrict__ Vb1,
                             const float* __restrict__ Vw2, const float* __restrict__ Vb2,
                             float* __restrict__ out, float inv_n) {
    __shared__ float g[128], a1[128], v1[128];
    int t = threadIdx.x;
    if (t < 128) g[t] = gsum[t] * inv_n + b3[t];
    __syncthreads();
    if (t < 128) {
        float s = Pb1[t];
        for (int f = 0; f < 128; ++f) s = fmaf(Pw1[t * 128 + f], g[f], s);
        a1[t] = fmaxf(s, 0.f);
    } else {
        int o = t - 128;
        float s = Vb1[o];
        for (int f = 0; f < 128; ++f) s = fmaf(Vw1[o * 128 + f], g[f], s);
        v1[o] = fmaxf(s, 0.f);
    }
    __syncthreads();
    if (t < 6) {
        float s = Pb2[t];
        for (int f = 0; f < 128; ++f) s = fmaf(Pw2[t * 128 + f], a1[f], s);
        out[t] = s;
    }
    if (t == 6) {
        float s = Vb2[0];
        for (int f = 0; f < 128; ++f) s = fmaf(Vw2[f], v1[f], s);
        out[6] = s;
    }
}

// ---------------------------------------------------------------------------
extern "C" void kernel_launch(void* const* d_in, const int* in_sizes, int n_in,
                              void* d_out, int out_size, void* d_ws, size_t ws_size,
                              hipStream_t stream) {
    const float* x    = (const float*)d_in[0];
    const int*   edges = (const int*)d_in[1];
    const float* W1l = (const float*)d_in[2];
    const float* b1  = (const float*)d_in[3];
    const float* W1r = (const float*)d_in[4];
    const float* W2l = (const float*)d_in[5];
    const float* b2  = (const float*)d_in[6];
    const float* W2r = (const float*)d_in[7];
    const float* W3l = (const float*)d_in[8];
    const float* b3  = (const float*)d_in[9];
    const float* W3r = (const float*)d_in[10];
    const float* Pw1 = (const float*)d_in[11];
    const float* Pb1 = (const float*)d_in[12];
    const float* Pw2 = (const float*)d_in[13];
    const float* Pb2 = (const float*)d_in[14];
    const float* Vw1 = (const float*)d_in[15];
    const float* Vb1 = (const float*)d_in[16];
    const float* Vw2 = (const float*)d_in[17];
    const float* Vb2 = (const float*)d_in[18];
    float* outp = (float*)d_out;

    const int E = in_sizes[1] / 2;

    // ---- workspace layout (int offsets, regions 256B-aligned) ----
    int*   ws_i = (int*)d_ws;
    float* ws_f = (float*)d_ws;
    size_t o_bcnt = 0;                 // NBC ints  (zeroed)
    size_t o_bcur = 256;               // NBC ints  (zeroed)
    size_t o_gsum = 512;               // 128 f32   (zeroed)
    size_t o_bptr = 640;               // NBC+1
    size_t o_rowp = 896;               // NN+1
    size_t o_bed  = 100928;            // E packed bucket edges
    size_t o_col  = o_bed + (size_t)E;           // E
    size_t o_whi  = ((o_col + (size_t)E + 63) / 64) * 64;  // 73728 shorts = 36864 ints
    size_t o_wlo  = o_whi + 36864;
    size_t o_x16  = o_wlo + 36864;               // NN*32 bf16 = NN*16 ints
    size_t o_aggr = o_x16 + (size_t)NN * 16;     // NN*128 bf16 = NN*64 ints
    size_t o_hA   = o_aggr + (size_t)NN * 64;
    size_t o_hB   = o_hA + (size_t)NN * 64;
    size_t o_h8   = o_hB + (size_t)NN * 64;      // NN*128 fp8 = NN*32 ints

    int*    bcnt    = ws_i + o_bcnt;
    int*    bcur    = ws_i + o_bcur;
    float*  gsum    = ws_f + o_gsum;
    int*    bptr    = ws_i + o_bptr;
    int*    row_ptr = ws_i + o_rowp;
    int*    bedges  = ws_i + o_bed;
    int*    col_src = ws_i + o_col;
    short*  whi     = (short*)(ws_i + o_whi);
    short*  wlo     = (short*)(ws_i + o_wlo);
    ushort* x16     = (ushort*)(ws_i + o_x16);
    ushort* aggr    = (ushort*)(ws_i + o_aggr);
    ushort* hA      = (ushort*)(ws_i + o_hA);
    ushort* hB      = (ushort*)(ws_i + o_hB);
    unsigned char* h8 = (unsigned char*)(ws_i + o_h8);

    short* W1l_hi = whi + 0;     short* W1l_lo = wlo + 0;
    short* W1r_hi = whi + 4096;  short* W1r_lo = wlo + 4096;
    short* W2l_hi = whi + 8192;  short* W2l_lo = wlo + 8192;
    short* W2r_hi = whi + 24576; short* W2r_lo = wlo + 24576;
    short* W3l_hi = whi + 40960; short* W3l_lo = wlo + 40960;
    short* W3r_hi = whi + 57344; short* W3r_lo = wlo + 57344;

    // zero bcnt, bcur, gsum
    hipMemsetAsync(d_ws, 0, 640 * sizeof(int), stream);

    const int TB = 256;
    dim3 blk(TB);

    // independent prep
    to_bf16<<<(NN * 32 / 4 + TB - 1) / TB, blk, 0, stream>>>(x, x16, NN * 32);
    split_weights<<<(73728 + TB - 1) / TB, blk, 0, stream>>>(
        W1l, W1r, W2l, W2r, W3l, W3r, whi, wlo);

    // bucketed CSR build (coarse 512-node buckets)
    bucket_hist<<<256, blk, 0, stream>>>(edges, E, bcnt);
    scan_bptr<<<1, 256, 0, stream>>>(bcnt, bptr);
    bucket_scatter<<<(E + SCAT_CHUNK - 1) / SCAT_CHUNK, blk, 0, stream>>>(
        edges, E, bptr, bcur, bedges);
    bucket_csr512<<<NBC, blk, 0, stream>>>(bedges, bptr, row_ptr, col_src);

    dim3 grid_agg((size_t)NN * 64 / TB);   // 25000: one wave per node
    dim3 grid_g(4 * 391);                  // 4 strips x 391 blocks (2 tiles each)

    // Layer 1 (K=32, relu): epilogue also writes fp8 hA for layer-2 gather
    aggregate32_bf16<<<grid_agg, blk, 0, stream>>>(x16, row_ptr, col_src, aggr, NN);
    gemm32<32, true, false, true><<<grid_g, blk, 0, stream>>>(
        aggr, x16, W1l_hi, W1l_lo, W1r_hi, W1r_lo, b1, hA, h8, nullptr);

    // Layer 2 (K=128, relu): epilogue writes fp8 hB for layer-3 gather
    aggregate128_fp8<<<grid_agg, blk, 0, stream>>>(h8, row_ptr, col_src, aggr, NN);
    gemm32<128, true, false, true><<<grid_g, blk, 0, stream>>>(
        aggr, hA, W2l_hi, W2l_lo, W2r_hi, W2r_lo, b2, hB, h8, nullptr);

    // Layer 3 (K=128, fused column-mean into gsum)
    aggregate128_fp8<<<grid_agg, blk, 0, stream>>>(h8, row_ptr, col_src, aggr, NN);
    gemm32<128, false, true, false><<<grid_g, blk, 0, stream>>>(
        aggr, hB, W3l_hi, W3l_lo, W3r_hi, W3r_lo, b3, nullptr, nullptr, gsum);

    // Heads (b3 folded into global mean here)
    heads_kernel<<<1, 256, 0, stream>>>(gsum, b3, Pw1, Pb1, Pw2, Pb2,
                                        Vw1, Vb1, Vw2, Vb2, outp,
                                        1.0f / (float)NN);
}

// Round 19
// 417.283 us; speedup vs baseline: 1.0300x; 1.0300x over previous
//
#include <hip/hip_runtime.h>
#include <hip/hip_bf16.h>

#define NN   100000
#define HIDD 128
#define NBC  196          // ceil(NN/512) coarse buckets of 512 nodes

typedef __attribute__((ext_vector_type(8))) short bf16x8;
typedef __attribute__((ext_vector_type(2))) float f32x2;
typedef __attribute__((ext_vector_type(4))) float f32x4;
typedef __attribute__((ext_vector_type(16))) float f32x16;

// RNE fp32 -> bf16 bits
__device__ __forceinline__ short bf16_rne(float v) {
    unsigned u = __float_as_uint(v);
    unsigned r = (u + 0x7fffu + ((u >> 16) & 1u)) >> 16;
    return (short)r;
}
__device__ __forceinline__ float bf16_to_f32(short b) {
    return __uint_as_float(((unsigned)(unsigned short)b) << 16);
}
__device__ __forceinline__ float bf16u_to_f32(ushort b) {
    return __uint_as_float(((unsigned)b) << 16);
}
__device__ __forceinline__ f32x2 unpack2p(unsigned u) {
    f32x2 r;
    r[0] = __uint_as_float((u & 0xFFFFu) << 16);
    r[1] = __uint_as_float(u & 0xFFFF0000u);
    return r;
}
__device__ __forceinline__ unsigned pack2(float a, float b) {
    return ((unsigned)(unsigned short)bf16_rne(a)) |
           (((unsigned)(unsigned short)bf16_rne(b)) << 16);
}

// ---------------------------------------------------------------------------
// Bucketed CSR build. bucket = dst >> 9 (512 nodes per bucket).
// ---------------------------------------------------------------------------
__global__ __launch_bounds__(256)
void bucket_hist(const int* __restrict__ edges, int n_edges,
                 int* __restrict__ bcnt) {
    __shared__ int lh[NBC];
    for (int i = threadIdx.x; i < NBC; i += 256) lh[i] = 0;
    __syncthreads();
    int stride = gridDim.x * blockDim.x;
    for (int e = blockIdx.x * blockDim.x + threadIdx.x; e < n_edges; e += stride) {
        int d = edges[n_edges + e];
        if ((unsigned)d < NN) atomicAdd(&lh[d >> 9], 1);
    }
    __syncthreads();
    for (int i = threadIdx.x; i < NBC; i += 256)
        if (lh[i]) atomicAdd(&bcnt[i], lh[i]);
}

__global__ void scan_bptr(const int* __restrict__ bcnt, int* __restrict__ bptr) {
    __shared__ int lds[256];
    int t = threadIdx.x;
    lds[t] = (t < NBC) ? bcnt[t] : 0;
    __syncthreads();
    for (int off = 1; off < 256; off <<= 1) {
        int u = (t >= off) ? lds[t - off] : 0;
        __syncthreads();
        lds[t] += u;
        __syncthreads();
    }
    if (t < NBC) bptr[t + 1] = lds[t];
    if (t == 0) bptr[0] = 0;
}

// Scatter edges into bucket regions as packed (dst_local<<17 | src).
#define SCAT_CHUNK 4096
__global__ __launch_bounds__(256)
void bucket_scatter(const int* __restrict__ edges, int n_edges,
                    const int* __restrict__ bptr, int* __restrict__ bcur,
                    int* __restrict__ bedges) {
    __shared__ int lh[NBC];
    __shared__ int lbase[NBC];
    int t = threadIdx.x;
    int base = blockIdx.x * SCAT_CHUNK;
    for (int i = t; i < NBC; i += 256) lh[i] = 0;
    __syncthreads();
#pragma unroll
    for (int i = 0; i < SCAT_CHUNK / 256; ++i) {
        int e = base + i * 256 + t;
        if (e < n_edges) {
            int d = edges[n_edges + e];
            if ((unsigned)d < NN) atomicAdd(&lh[d >> 9], 1);
        }
    }
    __syncthreads();
    for (int i = t; i < NBC; i += 256) {
        int c = lh[i];
        lbase[i] = (c > 0) ? atomicAdd(&bcur[i], c) : 0;
        lh[i] = 0;   // reuse as cursor
    }
    __syncthreads();
#pragma unroll
    for (int i = 0; i < SCAT_CHUNK / 256; ++i) {
        int e = base + i * 256 + t;
        if (e < n_edges) {
            int s = edges[e];
            int d = edges[n_edges + e];
            if ((unsigned)d < NN && (unsigned)s < NN) {
                int b = d >> 9;
                int off = atomicAdd(&lh[b], 1);
                bedges[bptr[b] + lbase[b] + off] = ((d & 511) << 17) | s;
            }
        }
    }
}

// One block per 512-node bucket: count -> pairwise scan -> place.
__global__ __launch_bounds__(256)
void bucket_csr512(const int* __restrict__ bedges, const int* __restrict__ bptr,
                   int* __restrict__ row_ptr, int* __restrict__ col_src) {
    __shared__ int lcnt[512];
    __shared__ int lsum[256];
    __shared__ int lexcl[512];
    int b = blockIdx.x;
    int t = threadIdx.x;
    int beg = bptr[b], end = bptr[b + 1];
    lcnt[t] = 0; lcnt[t + 256] = 0;
    __syncthreads();
    for (int e = beg + t; e < end; e += 256)
        atomicAdd(&lcnt[bedges[e] >> 17], 1);
    __syncthreads();
    int a0 = lcnt[2 * t], a1 = lcnt[2 * t + 1];
    lsum[t] = a0 + a1;
    __syncthreads();
    for (int off = 1; off < 256; off <<= 1) {
        int u = (t >= off) ? lsum[t - off] : 0;
        __syncthreads();
        lsum[t] += u;
        __syncthreads();
    }
    int pairExcl = lsum[t] - (a0 + a1);     // exclusive prefix of element 2t
    lexcl[2 * t]     = pairExcl;
    lexcl[2 * t + 1] = pairExcl + a0;
    int node0 = b << 9;
    int n0 = node0 + 2 * t, n1 = node0 + 2 * t + 1;
    if (n0 < NN) row_ptr[n0] = beg + pairExcl;
    if (n1 < NN) row_ptr[n1] = beg + pairExcl + a0;
    lcnt[2 * t] = 0; lcnt[2 * t + 1] = 0;   // reuse as cursors
    if (b == NBC - 1 && t == 0) row_ptr[NN] = end;
    __syncthreads();
    for (int e = beg + t; e < end; e += 256) {
        int p = bedges[e];
        int dl = p >> 17, src = p & 0x1FFFF;
        int pos = atomicAdd(&lcnt[dl], 1);
        col_src[beg + lexcl[dl] + pos] = src;
    }
}

// ---------------------------------------------------------------------------
// fp32 -> bf16 conversion (x)
// ---------------------------------------------------------------------------
__global__ void to_bf16(const float* __restrict__ in, ushort* __restrict__ out, int n) {
    int i = (blockIdx.x * blockDim.x + threadIdx.x) * 4;
    if (i + 3 >= n) {
        for (int k = i; k < n; ++k) out[k] = (ushort)bf16_rne(in[k]);
        return;
    }
    float4 v = *(const float4*)&in[i];
    unsigned lo = pack2(v.x, v.y), hi = pack2(v.z, v.w);
    *(uint2*)&out[i] = make_uint2(lo, hi);
}

// ---------------------------------------------------------------------------
// fp8 pull-mode mean aggregation: one wave per node, row = 128B.
// ---------------------------------------------------------------------------
__device__ __forceinline__ void acc_fp8x8p(f32x2* s, uint2 u) {
    s[0] += __builtin_amdgcn_cvt_pk_f32_fp8(u.x, false);
    s[1] += __builtin_amdgcn_cvt_pk_f32_fp8(u.x, true);
    s[2] += __builtin_amdgcn_cvt_pk_f32_fp8(u.y, false);
    s[3] += __builtin_amdgcn_cvt_pk_f32_fp8(u.y, true);
}

__global__ void aggregate128_fp8(const unsigned char* __restrict__ h8,
                                 const int* __restrict__ row_ptr,
                                 const int* __restrict__ col_src,
                                 ushort* __restrict__ aggr16, int n_nodes) {
    int node = (int)((blockIdx.x * (size_t)blockDim.x + threadIdx.x) >> 6);
    int lane = threadIdx.x & 63;
    if (node >= n_nodes) return;
    const int g   = lane >> 4;        // neighbor group 0..3
    const int seg = lane & 15;        // 8B segment within 128B row
    int beg = row_ptr[node], end = row_ptr[node + 1];
    f32x2 s[4];
#pragma unroll
    for (int e = 0; e < 4; ++e) s[e] = (f32x2){0.f, 0.f};
    int j = beg;
    for (; j + 16 <= end; j += 16) {               // 4 batches in flight
        int i0 = col_src[j + g];
        int i1 = col_src[j + 4 + g];
        int i2 = col_src[j + 8 + g];
        int i3 = col_src[j + 12 + g];
        uint2 u0 = *(const uint2*)&h8[(size_t)i0 * HIDD + seg * 8];
        uint2 u1 = *(const uint2*)&h8[(size_t)i1 * HIDD + seg * 8];
        uint2 u2 = *(const uint2*)&h8[(size_t)i2 * HIDD + seg * 8];
        uint2 u3 = *(const uint2*)&h8[(size_t)i3 * HIDD + seg * 8];
        acc_fp8x8p(s, u0);
        acc_fp8x8p(s, u1);
        acc_fp8x8p(s, u2);
        acc_fp8x8p(s, u3);
    }
    for (; j + 8 <= end; j += 8) {                 // 2 batches in flight
        int i0 = col_src[j + g];
        int i1 = col_src[j + 4 + g];
        uint2 u0 = *(const uint2*)&h8[(size_t)i0 * HIDD + seg * 8];
        uint2 u1 = *(const uint2*)&h8[(size_t)i1 * HIDD + seg * 8];
        acc_fp8x8p(s, u0);
        acc_fp8x8p(s, u1);
    }
    for (; j + 4 <= end; j += 4) {
        int i0 = col_src[j + g];
        uint2 u0 = *(const uint2*)&h8[(size_t)i0 * HIDD + seg * 8];
        acc_fp8x8p(s, u0);
    }
    int rem = end - j;
    if (g < rem) {                                 // masked tail, one step
        int i0 = col_src[j + g];
        uint2 u0 = *(const uint2*)&h8[(size_t)i0 * HIDD + seg * 8];
        acc_fp8x8p(s, u0);
    }
    // reduce across the 4 groups
#pragma unroll
    for (int e = 0; e < 4; ++e) {
        s[e][0] += __shfl_xor(s[e][0], 16);
        s[e][1] += __shfl_xor(s[e][1], 16);
        s[e][0] += __shfl_xor(s[e][0], 32);
        s[e][1] += __shfl_xor(s[e][1], 32);
    }
    float inv = (end > beg) ? 1.0f / (float)(end - beg) : 0.0f;
    if (lane < 16) {
        unsigned r0 = pack2(s[0][0] * inv, s[0][1] * inv);
        unsigned r1 = pack2(s[1][0] * inv, s[1][1] * inv);
        unsigned r2 = pack2(s[2][0] * inv, s[2][1] * inv);
        unsigned r3 = pack2(s[3][0] * inv, s[3][1] * inv);
        *(uint4*)&aggr16[(size_t)node * HIDD + seg * 8] = make_uint4(r0, r1, r2, r3);
    }
}

// One wave per node; 4 lanes x 16B cover one 64B row; 16 groups =>
// 16 neighbors per load instruction. Packed f32x2 accumulation.
__global__ void aggregate32_bf16(const ushort* __restrict__ x16,
                                 const int* __restrict__ row_ptr,
                                 const int* __restrict__ col_src,
                                 ushort* __restrict__ aggr16, int n_nodes) {
    int node = (int)((blockIdx.x * (size_t)blockDim.x + threadIdx.x) >> 6);
    int lane = threadIdx.x & 63;
    if (node >= n_nodes) return;
    const int g   = lane >> 2;        // neighbor group 0..15
    const int seg = lane & 3;         // 16B segment within 64B row
    int beg = row_ptr[node], end = row_ptr[node + 1];
    f32x2 s[4];
#pragma unroll
    for (int e = 0; e < 4; ++e) s[e] = (f32x2){0.f, 0.f};
    int j = beg;
    for (; j + 16 <= end; j += 16) {
        int i0 = col_src[j + g];
        uint4 u = *(const uint4*)&x16[(size_t)i0 * 32 + seg * 8];
        s[0] += unpack2p(u.x);
        s[1] += unpack2p(u.y);
        s[2] += unpack2p(u.z);
        s[3] += unpack2p(u.w);
    }
    int rem = end - j;
    if (g < rem) {                                 // masked tail (up to 15)
        int i0 = col_src[j + g];
        uint4 u = *(const uint4*)&x16[(size_t)i0 * 32 + seg * 8];
        s[0] += unpack2p(u.x);
        s[1] += unpack2p(u.y);
        s[2] += unpack2p(u.z);
        s[3] += unpack2p(u.w);
    }
    // reduce across the 16 groups
#pragma unroll
    for (int e = 0; e < 4; ++e) {
#pragma unroll
        for (int h = 0; h < 2; ++h) {
            s[e][h] += __shfl_xor(s[e][h], 4);
            s[e][h] += __shfl_xor(s[e][h], 8);
            s[e][h] += __shfl_xor(s[e][h], 16);
            s[e][h] += __shfl_xor(s[e][h], 32);
        }
    }
    float inv = (end > beg) ? 1.0f / (float)(end - beg) : 0.0f;
    if (lane < 4) {
        unsigned r0 = pack2(s[0][0] * inv, s[0][1] * inv);
        unsigned r1 = pack2(s[1][0] * inv, s[1][1] * inv);
        unsigned r2 = pack2(s[2][0] * inv, s[2][1] * inv);
        unsigned r3 = pack2(s[3][0] * inv, s[3][1] * inv);
        *(uint4*)&aggr16[(size_t)node * 32 + seg * 8] = make_uint4(r0, r1, r2, r3);
    }
}

// ---------------------------------------------------------------------------
// Weight pre-split: fp32 -> (hi, lo) bf16 planes, all 6 conv matrices.
// ---------------------------------------------------------------------------
__global__ void split_weights(const float* __restrict__ W1l, const float* __restrict__ W1r,
                              const float* __restrict__ W2l, const float* __restrict__ W2r,
                              const float* __restrict__ W3l, const float* __restrict__ W3r,
                              short* __restrict__ whi, short* __restrict__ wlo) {
    int i = blockIdx.x * blockDim.x + threadIdx.x;
    if (i >= 73728) return;
    const float* src; int off;
    if (i < 4096)       { src = W1l; off = 0; }
    else if (i < 8192)  { src = W1r; off = 4096; }
    else if (i < 24576) { src = W2l; off = 8192; }
    else if (i < 40960) { src = W2r; off = 24576; }
    else if (i < 57344) { src = W3l; off = 40960; }
    else                { src = W3r; off = 57344; }
    float v = src[i - off];
    short h = bf16_rne(v);
    float l = v - bf16_to_f32(h);
    whi[i] = h;
    wlo[i] = bf16_rne(l);
}

// ---------------------------------------------------------------------------
// 32x32x16-MFMA dual GEMM — v4 (r16 geometry + 8-wave blocks for TLP):
// Block = 512 thr = 8 waves sharing ONE 64KB W-stage for a 64-col half
// (blockIdx&1). Wave = (strip = wave&1, row-quarter = wave>>1):
// block tile = 128 rows x 64 cols. 2 blocks/CU (128KB LDS) x 8 waves
// = 16 waves/CU = 4/SIMD — double r16's TLP at identical traffic
// (r18's 4-strip split quadrupled HBM A-reads: FETCH 50->214MB; reverted).
// Per wave-tile: 16 A-loads + 32 ds_read_b128 + 32 MFMA. Grid 1564 = 1 tile.
// FP8OUT: epilogue also emits fp8 e4m3 copy for the next layer's gather.
// ---------------------------------------------------------------------------
template <int KA, bool RELU, bool MEAN, bool FP8OUT>
__global__ __launch_bounds__(512, 4)
void gemm32(const ushort* __restrict__ inA, const ushort* __restrict__ inB,
            const short* __restrict__ WAhi, const short* __restrict__ WAlo,
            const short* __restrict__ WBhi, const short* __restrict__ WBlo,
            const float* __restrict__ bias,
            ushort* __restrict__ out, unsigned char* __restrict__ out8,
            float* __restrict__ gsum) {
    constexpr int NCH = KA / 16;            // k-chunks of 16
    constexpr int NT  = (NN + 127) / 128;   // 782 tiles of 128 rows
    __shared__ __align__(16) ushort sW[4096 * NCH];  // 64KB at KA=128

    const int t = threadIdx.x;
    const int wave = t >> 6, lane = t & 63;
    const int half  = blockIdx.x & 1;
    const int strip = wave & 1;             // 32-col strip within the half
    const int rquar = wave >> 1;            // 32-row quarter of the 128-row tile
    const int col = lane & 31;
    const int kh  = lane >> 5;              // k-half of the fragment
    const int o0 = half * 64 + strip * 32;

    // ---- stage W (hi+lo, both ops) for this 64-col half; frag-linear ----
    for (int i = t; i < 512 * NCH; i += 512) {
        int st  = i / (256 * NCH);
        int rem = i % (256 * NCH);
        int f   = rem >> 6;                 // (op*NCH+ch)*2+pl
        int w   = i & 63;
        int wkh = w >> 5, wcol = w & 31;
        int op = f / (NCH * 2);
        int r2 = f % (NCH * 2);
        int ch = r2 >> 1, pl = r2 & 1;
        const short* Wp = op ? (pl ? WBlo : WBhi) : (pl ? WAlo : WAhi);
        bf16x8 v = *(const bf16x8*)&Wp[(size_t)(half * 64 + st * 32 + wcol) * KA
                                       + ch * 16 + wkh * 8];
        *(bf16x8*)&sW[(size_t)i * 8] = v;
    }
    __syncthreads();

    const int sbase = strip * (2048 * NCH) + kh * 256 + col * 8;
    const float bv = MEAN ? 0.f : bias[o0 + col];
    float csum = 0.f;
    const int step = gridDim.x >> 1;

    for (int rt = blockIdx.x >> 1; rt < NT; rt += step) {
        const int r0 = rt * 128 + rquar * 32;
        const int ar = min(r0 + col, NN - 1);     // clamped load row
        f32x16 acc = {0.f,0.f,0.f,0.f,0.f,0.f,0.f,0.f,
                      0.f,0.f,0.f,0.f,0.f,0.f,0.f,0.f};
#pragma unroll
        for (int op = 0; op < 2; ++op) {
            const ushort* __restrict__ in = op ? inB : inA;
            const ushort* ab = in + (size_t)ar * KA + kh * 8;
            bf16x8 a[NCH];
#pragma unroll
            for (int ch = 0; ch < NCH; ++ch) a[ch] = *(const bf16x8*)(ab + ch * 16);
#pragma unroll
            for (int ch = 0; ch < NCH; ++ch) {
                bf16x8 wh = *(const bf16x8*)&sW[sbase + ((op * NCH + ch) * 2 + 0) * 512];
                acc = __builtin_amdgcn_mfma_f32_32x32x16_bf16(a[ch], wh, acc, 0, 0, 0);
                bf16x8 wl = *(const bf16x8*)&sW[sbase + ((op * NCH + ch) * 2 + 1) * 512];
                acc = __builtin_amdgcn_mfma_f32_32x32x16_bf16(a[ch], wl, acc, 0, 0, 0);
            }
        }
        if (r0 < NN) {                      // whole 32-row subtile valid or not
            if (!MEAN) {
                const int o = o0 + col;
                const int rb = r0 + 4 * kh;
#pragma unroll
                for (int reg = 0; reg < 16; reg += 2) {
                    int ra = rb + (reg & 3) + 8 * (reg >> 2);   // pair rows ra, ra+1
                    float v0 = acc[reg] + bv;
                    float v1 = acc[reg + 1] + bv;
                    if (RELU) { v0 = fmaxf(v0, 0.f); v1 = fmaxf(v1, 0.f); }
                    out[(size_t)ra * HIDD + o]       = (ushort)bf16_rne(v0);
                    out[(size_t)(ra + 1) * HIDD + o] = (ushort)bf16_rne(v1);
                    if (FP8OUT) {
                        unsigned w = __builtin_amdgcn_cvt_pk_fp8_f32(v0, v1, 0u, false);
                        out8[(size_t)ra * HIDD + o]       = (unsigned char)(w & 0xFF);
                        out8[(size_t)(ra + 1) * HIDD + o] = (unsigned char)((w >> 8) & 0xFF);
                    }
                }
            } else {
#pragma unroll
                for (int reg = 0; reg < 16; ++reg) csum += acc[reg];
            }
        }
    }

    if (MEAN) {
        csum += __shfl_xor(csum, 32);       // combine the two k-half row-subsets
        if (lane < 32) atomicAdd(&gsum[o0 + col], csum);
    }
}

// ---------------------------------------------------------------------------
// Heads: g = gsum/N + b3; logits = relu(g@Pw1.T+Pb1)@Pw2.T+Pb2; value likewise.
// ---------------------------------------------------------------------------
__global__ void heads_kernel(const float* __restrict__ gsum,
                             const float* __restrict__ b3,
                             const float* __restrict__ Pw1, const float* __restrict__ Pb1,
                             const float* __restrict__ Pw2, const float* __restrict__ Pb2,
                             const float* __restrict__ Vw1, const float* __restrict__ Vb1,
                             const float* __restrict__ Vw2, const float* __restrict__ Vb2,
                             float* __restrict__ out, float inv_n) {
    __shared__ float g[128], a1[128], v1[128];
    int t = threadIdx.x;
    if (t < 128) g[t] = gsum[t] * inv_n + b3[t];
    __syncthreads();
    if (t < 128) {
        float s = Pb1[t];
        for (int f = 0; f < 128; ++f) s = fmaf(Pw1[t * 128 + f], g[f], s);
        a1[t] = fmaxf(s, 0.f);
    } else {
        int o = t - 128;
        float s = Vb1[o];
        for (int f = 0; f < 128; ++f) s = fmaf(Vw1[o * 128 + f], g[f], s);
        v1[o] = fmaxf(s, 0.f);
    }
    __syncthreads();
    if (t < 6) {
        float s = Pb2[t];
        for (int f = 0; f < 128; ++f) s = fmaf(Pw2[t * 128 + f], a1[f], s);
        out[t] = s;
    }
    if (t == 6) {
        float s = Vb2[0];
        for (int f = 0; f < 128; ++f) s = fmaf(Vw2[f], v1[f], s);
        out[6] = s;
    }
}

// ---------------------------------------------------------------------------
extern "C" void kernel_launch(void* const* d_in, const int* in_sizes, int n_in,
                              void* d_out, int out_size, void* d_ws, size_t ws_size,
                              hipStream_t stream) {
    const float* x    = (const float*)d_in[0];
    const int*   edges = (const int*)d_in[1];
    const float* W1l = (const float*)d_in[2];
    const float* b1  = (const float*)d_in[3];
    const float* W1r = (const float*)d_in[4];
    const float* W2l = (const float*)d_in[5];
    const float* b2  = (const float*)d_in[6];
    const float* W2r = (const float*)d_in[7];
    const float* W3l = (const float*)d_in[8];
    const float* b3  = (const float*)d_in[9];
    const float* W3r = (const float*)d_in[10];
    const float* Pw1 = (const float*)d_in[11];
    const float* Pb1 = (const float*)d_in[12];
    const float* Pw2 = (const float*)d_in[13];
    const float* Pb2 = (const float*)d_in[14];
    const float* Vw1 = (const float*)d_in[15];
    const float* Vb1 = (const float*)d_in[16];
    const float* Vw2 = (const float*)d_in[17];
    const float* Vb2 = (const float*)d_in[18];
    float* outp = (float*)d_out;

    const int E = in_sizes[1] / 2;

    // ---- workspace layout (int offsets, regions 256B-aligned) ----
    int*   ws_i = (int*)d_ws;
    float* ws_f = (float*)d_ws;
    size_t o_bcnt = 0;                 // NBC ints  (zeroed)
    size_t o_bcur = 256;               // NBC ints  (zeroed)
    size_t o_gsum = 512;               // 128 f32   (zeroed)
    size_t o_bptr = 640;               // NBC+1
    size_t o_rowp = 896;               // NN+1
    size_t o_bed  = 100928;            // E packed bucket edges
    size_t o_col  = o_bed + (size_t)E;           // E
    size_t o_whi  = ((o_col + (size_t)E + 63) / 64) * 64;  // 73728 shorts = 36864 ints
    size_t o_wlo  = o_whi + 36864;
    size_t o_x16  = o_wlo + 36864;               // NN*32 bf16 = NN*16 ints
    size_t o_aggr = o_x16 + (size_t)NN * 16;     // NN*128 bf16 = NN*64 ints
    size_t o_hA   = o_aggr + (size_t)NN * 64;
    size_t o_hB   = o_hA + (size_t)NN * 64;
    size_t o_h8   = o_hB + (size_t)NN * 64;      // NN*128 fp8 = NN*32 ints

    int*    bcnt    = ws_i + o_bcnt;
    int*    bcur    = ws_i + o_bcur;
    float*  gsum    = ws_f + o_gsum;
    int*    bptr    = ws_i + o_bptr;
    int*    row_ptr = ws_i + o_rowp;
    int*    bedges  = ws_i + o_bed;
    int*    col_src = ws_i + o_col;
    short*  whi     = (short*)(ws_i + o_whi);
    short*  wlo     = (short*)(ws_i + o_wlo);
    ushort* x16     = (ushort*)(ws_i + o_x16);
    ushort* aggr    = (ushort*)(ws_i + o_aggr);
    ushort* hA      = (ushort*)(ws_i + o_hA);
    ushort* hB      = (ushort*)(ws_i + o_hB);
    unsigned char* h8 = (unsigned char*)(ws_i + o_h8);

    short* W1l_hi = whi + 0;     short* W1l_lo = wlo + 0;
    short* W1r_hi = whi + 4096;  short* W1r_lo = wlo + 4096;
    short* W2l_hi = whi + 8192;  short* W2l_lo = wlo + 8192;
    short* W2r_hi = whi + 24576; short* W2r_lo = wlo + 24576;
    short* W3l_hi = whi + 40960; short* W3l_lo = wlo + 40960;
    short* W3r_hi = whi + 57344; short* W3r_lo = wlo + 57344;

    // zero bcnt, bcur, gsum
    hipMemsetAsync(d_ws, 0, 640 * sizeof(int), stream);

    const int TB = 256;
    dim3 blk(TB);
    dim3 blk512(512);

    // independent prep
    to_bf16<<<(NN * 32 / 4 + TB - 1) / TB, blk, 0, stream>>>(x, x16, NN * 32);
    split_weights<<<(73728 + TB - 1) / TB, blk, 0, stream>>>(
        W1l, W1r, W2l, W2r, W3l, W3r, whi, wlo);

    // bucketed CSR build (coarse 512-node buckets)
    bucket_hist<<<256, blk, 0, stream>>>(edges, E, bcnt);
    scan_bptr<<<1, 256, 0, stream>>>(bcnt, bptr);
    bucket_scatter<<<(E + SCAT_CHUNK - 1) / SCAT_CHUNK, blk, 0, stream>>>(
        edges, E, bptr, bcur, bedges);
    bucket_csr512<<<NBC, blk, 0, stream>>>(bedges, bptr, row_ptr, col_src);

    dim3 grid_agg((size_t)NN * 64 / TB);   // 25000: one wave per node
    dim3 grid_g(1564);                     // 2 col-halves x 782 tiles (1 each)

    // Layer 1 (K=32, relu): epilogue also writes fp8 hA for layer-2 gather
    aggregate32_bf16<<<grid_agg, blk, 0, stream>>>(x16, row_ptr, col_src, aggr, NN);
    gemm32<32, true, false, true><<<grid_g, blk512, 0, stream>>>(
        aggr, x16, W1l_hi, W1l_lo, W1r_hi, W1r_lo, b1, hA, h8, nullptr);

    // Layer 2 (K=128, relu): epilogue writes fp8 hB for layer-3 gather
    aggregate128_fp8<<<grid_agg, blk, 0, stream>>>(h8, row_ptr, col_src, aggr, NN);
    gemm32<128, true, false, true><<<grid_g, blk512, 0, stream>>>(
        aggr, hA, W2l_hi, W2l_lo, W2r_hi, W2r_lo, b2, hB, h8, nullptr);

    // Layer 3 (K=128, fused column-mean into gsum)
    aggregate128_fp8<<<grid_agg, blk, 0, stream>>>(h8, row_ptr, col_src, aggr, NN);
    gemm32<128, false, true, false><<<grid_g, blk512, 0, stream>>>(
        aggr, hB, W3l_hi, W3l_lo, W3r_hi, W3r_lo, b3, nullptr, nullptr, gsum);

    // Heads (b3 folded into global mean here)
    heads_kernel<<<1, 256, 0, stream>>>(gsum, b3, Pw1, Pb1, Pw2, Pb2,
                                        Vw1, Vb1, Vw2, Vb2, outp,
                                        1.0f / (float)NN);
}

// Round 20
// 351.825 us; speedup vs baseline: 1.2217x; 1.1861x over previous
//
#include <hip/hip_runtime.h>
#include <hip/hip_bf16.h>

#define NN   100000
#define HIDD 128
#define NBC  196          // ceil(NN/512) coarse buckets of 512 nodes

typedef __attribute__((ext_vector_type(8))) short bf16x8;
typedef __attribute__((ext_vector_type(2))) float f32x2;
typedef __attribute__((ext_vector_type(4))) float f32x4;
typedef __attribute__((ext_vector_type(16))) float f32x16;

// RNE fp32 -> bf16 bits
__device__ __forceinline__ short bf16_rne(float v) {
    unsigned u = __float_as_uint(v);
    unsigned r = (u + 0x7fffu + ((u >> 16) & 1u)) >> 16;
    return (short)r;
}
__device__ __forceinline__ float bf16_to_f32(short b) {
    return __uint_as_float(((unsigned)(unsigned short)b) << 16);
}
__device__ __forceinline__ float bf16u_to_f32(ushort b) {
    return __uint_as_float(((unsigned)b) << 16);
}
__device__ __forceinline__ f32x2 unpack2p(unsigned u) {
    f32x2 r;
    r[0] = __uint_as_float((u & 0xFFFFu) << 16);
    r[1] = __uint_as_float(u & 0xFFFF0000u);
    return r;
}
__device__ __forceinline__ unsigned pack2(float a, float b) {
    return ((unsigned)(unsigned short)bf16_rne(a)) |
           (((unsigned)(unsigned short)bf16_rne(b)) << 16);
}

// ---------------------------------------------------------------------------
// Bucketed CSR build. bucket = dst >> 9 (512 nodes per bucket).
// ---------------------------------------------------------------------------
__global__ __launch_bounds__(256)
void bucket_hist(const int* __restrict__ edges, int n_edges,
                 int* __restrict__ bcnt) {
    __shared__ int lh[NBC];
    for (int i = threadIdx.x; i < NBC; i += 256) lh[i] = 0;
    __syncthreads();
    int stride = gridDim.x * blockDim.x;
    for (int e = blockIdx.x * blockDim.x + threadIdx.x; e < n_edges; e += stride) {
        int d = edges[n_edges + e];
        if ((unsigned)d < NN) atomicAdd(&lh[d >> 9], 1);
    }
    __syncthreads();
    for (int i = threadIdx.x; i < NBC; i += 256)
        if (lh[i]) atomicAdd(&bcnt[i], lh[i]);
}

__global__ void scan_bptr(const int* __restrict__ bcnt, int* __restrict__ bptr) {
    __shared__ int lds[256];
    int t = threadIdx.x;
    lds[t] = (t < NBC) ? bcnt[t] : 0;
    __syncthreads();
    for (int off = 1; off < 256; off <<= 1) {
        int u = (t >= off) ? lds[t - off] : 0;
        __syncthreads();
        lds[t] += u;
        __syncthreads();
    }
    if (t < NBC) bptr[t + 1] = lds[t];
    if (t == 0) bptr[0] = 0;
}

// Scatter edges into bucket regions as packed (dst_local<<17 | src).
#define SCAT_CHUNK 4096
__global__ __launch_bounds__(256)
void bucket_scatter(const int* __restrict__ edges, int n_edges,
                    const int* __restrict__ bptr, int* __restrict__ bcur,
                    int* __restrict__ bedges) {
    __shared__ int lh[NBC];
    __shared__ int lbase[NBC];
    int t = threadIdx.x;
    int base = blockIdx.x * SCAT_CHUNK;
    for (int i = t; i < NBC; i += 256) lh[i] = 0;
    __syncthreads();
#pragma unroll
    for (int i = 0; i < SCAT_CHUNK / 256; ++i) {
        int e = base + i * 256 + t;
        if (e < n_edges) {
            int d = edges[n_edges + e];
            if ((unsigned)d < NN) atomicAdd(&lh[d >> 9], 1);
        }
    }
    __syncthreads();
    for (int i = t; i < NBC; i += 256) {
        int c = lh[i];
        lbase[i] = (c > 0) ? atomicAdd(&bcur[i], c) : 0;
        lh[i] = 0;   // reuse as cursor
    }
    __syncthreads();
#pragma unroll
    for (int i = 0; i < SCAT_CHUNK / 256; ++i) {
        int e = base + i * 256 + t;
        if (e < n_edges) {
            int s = edges[e];
            int d = edges[n_edges + e];
            if ((unsigned)d < NN && (unsigned)s < NN) {
                int b = d >> 9;
                int off = atomicAdd(&lh[b], 1);
                bedges[bptr[b] + lbase[b] + off] = ((d & 511) << 17) | s;
            }
        }
    }
}

// One block per 512-node bucket: count -> pairwise scan -> place.
__global__ __launch_bounds__(256)
void bucket_csr512(const int* __restrict__ bedges, const int* __restrict__ bptr,
                   int* __restrict__ row_ptr, int* __restrict__ col_src) {
    __shared__ int lcnt[512];
    __shared__ int lsum[256];
    __shared__ int lexcl[512];
    int b = blockIdx.x;
    int t = threadIdx.x;
    int beg = bptr[b], end = bptr[b + 1];
    lcnt[t] = 0; lcnt[t + 256] = 0;
    __syncthreads();
    for (int e = beg + t; e < end; e += 256)
        atomicAdd(&lcnt[bedges[e] >> 17], 1);
    __syncthreads();
    int a0 = lcnt[2 * t], a1 = lcnt[2 * t + 1];
    lsum[t] = a0 + a1;
    __syncthreads();
    for (int off = 1; off < 256; off <<= 1) {
        int u = (t >= off) ? lsum[t - off] : 0;
        __syncthreads();
        lsum[t] += u;
        __syncthreads();
    }
    int pairExcl = lsum[t] - (a0 + a1);     // exclusive prefix of element 2t
    lexcl[2 * t]     = pairExcl;
    lexcl[2 * t + 1] = pairExcl + a0;
    int node0 = b << 9;
    int n0 = node0 + 2 * t, n1 = node0 + 2 * t + 1;
    if (n0 < NN) row_ptr[n0] = beg + pairExcl;
    if (n1 < NN) row_ptr[n1] = beg + pairExcl + a0;
    lcnt[2 * t] = 0; lcnt[2 * t + 1] = 0;   // reuse as cursors
    if (b == NBC - 1 && t == 0) row_ptr[NN] = end;
    __syncthreads();
    for (int e = beg + t; e < end; e += 256) {
        int p = bedges[e];
        int dl = p >> 17, src = p & 0x1FFFF;
        int pos = atomicAdd(&lcnt[dl], 1);
        col_src[beg + lexcl[dl] + pos] = src;
    }
}

// ---------------------------------------------------------------------------
// fp32 -> bf16 conversion (x)
// ---------------------------------------------------------------------------
__global__ void to_bf16(const float* __restrict__ in, ushort* __restrict__ out, int n) {
    int i = (blockIdx.x * blockDim.x + threadIdx.x) * 4;
    if (i + 3 >= n) {
        for (int k = i; k < n; ++k) out[k] = (ushort)bf16_rne(in[k]);
        return;
    }
    float4 v = *(const float4*)&in[i];
    unsigned lo = pack2(v.x, v.y), hi = pack2(v.z, v.w);
    *(uint2*)&out[i] = make_uint2(lo, hi);
}

// ---------------------------------------------------------------------------
// fp8 pull-mode mean aggregation: one wave per node, row = 128B.
// ---------------------------------------------------------------------------
__device__ __forceinline__ void acc_fp8x8p(f32x2* s, uint2 u) {
    s[0] += __builtin_amdgcn_cvt_pk_f32_fp8(u.x, false);
    s[1] += __builtin_amdgcn_cvt_pk_f32_fp8(u.x, true);
    s[2] += __builtin_amdgcn_cvt_pk_f32_fp8(u.y, false);
    s[3] += __builtin_amdgcn_cvt_pk_f32_fp8(u.y, true);
}

__global__ void aggregate128_fp8(const unsigned char* __restrict__ h8,
                                 const int* __restrict__ row_ptr,
                                 const int* __restrict__ col_src,
                                 ushort* __restrict__ aggr16, int n_nodes) {
    int node = (int)((blockIdx.x * (size_t)blockDim.x + threadIdx.x) >> 6);
    int lane = threadIdx.x & 63;
    if (node >= n_nodes) return;
    const int g   = lane >> 4;        // neighbor group 0..3
    const int seg = lane & 15;        // 8B segment within 128B row
    int beg = row_ptr[node], end = row_ptr[node + 1];
    f32x2 s[4];
#pragma unroll
    for (int e = 0; e < 4; ++e) s[e] = (f32x2){0.f, 0.f};
    int j = beg;
    for (; j + 16 <= end; j += 16) {               // 4 batches in flight
        int i0 = col_src[j + g];
        int i1 = col_src[j + 4 + g];
        int i2 = col_src[j + 8 + g];
        int i3 = col_src[j + 12 + g];
        uint2 u0 = *(const uint2*)&h8[(size_t)i0 * HIDD + seg * 8];
        uint2 u1 = *(const uint2*)&h8[(size_t)i1 * HIDD + seg * 8];
        uint2 u2 = *(const uint2*)&h8[(size_t)i2 * HIDD + seg * 8];
        uint2 u3 = *(const uint2*)&h8[(size_t)i3 * HIDD + seg * 8];
        acc_fp8x8p(s, u0);
        acc_fp8x8p(s, u1);
        acc_fp8x8p(s, u2);
        acc_fp8x8p(s, u3);
    }
    for (; j + 8 <= end; j += 8) {                 // 2 batches in flight
        int i0 = col_src[j + g];
        int i1 = col_src[j + 4 + g];
        uint2 u0 = *(const uint2*)&h8[(size_t)i0 * HIDD + seg * 8];
        uint2 u1 = *(const uint2*)&h8[(size_t)i1 * HIDD + seg * 8];
        acc_fp8x8p(s, u0);
        acc_fp8x8p(s, u1);
    }
    for (; j + 4 <= end; j += 4) {
        int i0 = col_src[j + g];
        uint2 u0 = *(const uint2*)&h8[(size_t)i0 * HIDD + seg * 8];
        acc_fp8x8p(s, u0);
    }
    int rem = end - j;
    if (g < rem) {                                 // masked tail, one step
        int i0 = col_src[j + g];
        uint2 u0 = *(const uint2*)&h8[(size_t)i0 * HIDD + seg * 8];
        acc_fp8x8p(s, u0);
    }
    // reduce across the 4 groups
#pragma unroll
    for (int e = 0; e < 4; ++e) {
        s[e][0] += __shfl_xor(s[e][0], 16);
        s[e][1] += __shfl_xor(s[e][1], 16);
        s[e][0] += __shfl_xor(s[e][0], 32);
        s[e][1] += __shfl_xor(s[e][1], 32);
    }
    float inv = (end > beg) ? 1.0f / (float)(end - beg) : 0.0f;
    if (lane < 16) {
        unsigned r0 = pack2(s[0][0] * inv, s[0][1] * inv);
        unsigned r1 = pack2(s[1][0] * inv, s[1][1] * inv);
        unsigned r2 = pack2(s[2][0] * inv, s[2][1] * inv);
        unsigned r3 = pack2(s[3][0] * inv, s[3][1] * inv);
        *(uint4*)&aggr16[(size_t)node * HIDD + seg * 8] = make_uint4(r0, r1, r2, r3);
    }
}

// One wave per node; 4 lanes x 16B cover one 64B row; 16 groups =>
// 16 neighbors per load instruction. Packed f32x2 accumulation.
__global__ void aggregate32_bf16(const ushort* __restrict__ x16,
                                 const int* __restrict__ row_ptr,
                                 const int* __restrict__ col_src,
                                 ushort* __restrict__ aggr16, int n_nodes) {
    int node = (int)((blockIdx.x * (size_t)blockDim.x + threadIdx.x) >> 6);
    int lane = threadIdx.x & 63;
    if (node >= n_nodes) return;
    const int g   = lane >> 2;        // neighbor group 0..15
    const int seg = lane & 3;         // 16B segment within 64B row
    int beg = row_ptr[node], end = row_ptr[node + 1];
    f32x2 s[4];
#pragma unroll
    for (int e = 0; e < 4; ++e) s[e] = (f32x2){0.f, 0.f};
    int j = beg;
    for (; j + 16 <= end; j += 16) {
        int i0 = col_src[j + g];
        uint4 u = *(const uint4*)&x16[(size_t)i0 * 32 + seg * 8];
        s[0] += unpack2p(u.x);
        s[1] += unpack2p(u.y);
        s[2] += unpack2p(u.z);
        s[3] += unpack2p(u.w);
    }
    int rem = end - j;
    if (g < rem) {                                 // masked tail (up to 15)
        int i0 = col_src[j + g];
        uint4 u = *(const uint4*)&x16[(size_t)i0 * 32 + seg * 8];
        s[0] += unpack2p(u.x);
        s[1] += unpack2p(u.y);
        s[2] += unpack2p(u.z);
        s[3] += unpack2p(u.w);
    }
    // reduce across the 16 groups
#pragma unroll
    for (int e = 0; e < 4; ++e) {
#pragma unroll
        for (int h = 0; h < 2; ++h) {
            s[e][h] += __shfl_xor(s[e][h], 4);
            s[e][h] += __shfl_xor(s[e][h], 8);
            s[e][h] += __shfl_xor(s[e][h], 16);
            s[e][h] += __shfl_xor(s[e][h], 32);
        }
    }
    float inv = (end > beg) ? 1.0f / (float)(end - beg) : 0.0f;
    if (lane < 4) {
        unsigned r0 = pack2(s[0][0] * inv, s[0][1] * inv);
        unsigned r1 = pack2(s[1][0] * inv, s[1][1] * inv);
        unsigned r2 = pack2(s[2][0] * inv, s[2][1] * inv);
        unsigned r3 = pack2(s[3][0] * inv, s[3][1] * inv);
        *(uint4*)&aggr16[(size_t)node * 32 + seg * 8] = make_uint4(r0, r1, r2, r3);
    }
}

// ---------------------------------------------------------------------------
// Weight pre-split: fp32 -> (hi, lo) bf16 planes, all 6 conv matrices.
// ---------------------------------------------------------------------------
__global__ void split_weights(const float* __restrict__ W1l, const float* __restrict__ W1r,
                              const float* __restrict__ W2l, const float* __restrict__ W2r,
                              const float* __restrict__ W3l, const float* __restrict__ W3r,
                              short* __restrict__ whi, short* __restrict__ wlo) {
    int i = blockIdx.x * blockDim.x + threadIdx.x;
    if (i >= 73728) return;
    const float* src; int off;
    if (i < 4096)       { src = W1l; off = 0; }
    else if (i < 8192)  { src = W1r; off = 4096; }
    else if (i < 24576) { src = W2l; off = 8192; }
    else if (i < 40960) { src = W2r; off = 24576; }
    else if (i < 57344) { src = W3l; off = 40960; }
    else                { src = W3r; off = 57344; }
    float v = src[i - off];
    short h = bf16_rne(v);
    float l = v - bf16_to_f32(h);
    whi[i] = h;
    wlo[i] = bf16_rne(l);
}

// ---------------------------------------------------------------------------
// 32x32x16-MFMA dual GEMM — v5: 8-wave blocks + LOCKSTEP col-half pairing.
// r19 (1 tile/block, grid 1564) broke the (2i,2i+1) half-pair co-scheduling
// -> partial-line writes & duplicate A-reads stopped merging in cache
// (FETCH 50->109MB, WRITE 37->117MB, 47->127us). Grid-stride with grid=512
// restores r16's lockstep pairing while keeping 8 waves (4 waves/SIMD).
// Block = 512 thr = 8 waves, 64KB W-stage per 64-col half; wave =
// (strip = wave&1, row-quarter = wave>>1); tile = 128 rows; NT=782; step 256.
// FP8OUT: epilogue also emits fp8 e4m3 copy for the next layer's gather.
// ---------------------------------------------------------------------------
template <int KA, bool RELU, bool MEAN, bool FP8OUT>
__global__ __launch_bounds__(512, 4)
void gemm32(const ushort* __restrict__ inA, const ushort* __restrict__ inB,
            const short* __restrict__ WAhi, const short* __restrict__ WAlo,
            const short* __restrict__ WBhi, const short* __restrict__ WBlo,
            const float* __restrict__ bias,
            ushort* __restrict__ out, unsigned char* __restrict__ out8,
            float* __restrict__ gsum) {
    constexpr int NCH = KA / 16;            // k-chunks of 16
    constexpr int NT  = (NN + 127) / 128;   // 782 tiles of 128 rows
    __shared__ __align__(16) ushort sW[4096 * NCH];  // 64KB at KA=128

    const int t = threadIdx.x;
    const int wave = t >> 6, lane = t & 63;
    const int half  = blockIdx.x & 1;
    const int strip = wave & 1;             // 32-col strip within the half
    const int rquar = wave >> 1;            // 32-row quarter of the 128-row tile
    const int col = lane & 31;
    const int kh  = lane >> 5;              // k-half of the fragment
    const int o0 = half * 64 + strip * 32;

    // ---- stage W (hi+lo, both ops) for this 64-col half; frag-linear ----
    for (int i = t; i < 512 * NCH; i += 512) {
        int st  = i / (256 * NCH);
        int rem = i % (256 * NCH);
        int f   = rem >> 6;                 // (op*NCH+ch)*2+pl
        int w   = i & 63;
        int wkh = w >> 5, wcol = w & 31;
        int op = f / (NCH * 2);
        int r2 = f % (NCH * 2);
        int ch = r2 >> 1, pl = r2 & 1;
        const short* Wp = op ? (pl ? WBlo : WBhi) : (pl ? WAlo : WAhi);
        bf16x8 v = *(const bf16x8*)&Wp[(size_t)(half * 64 + st * 32 + wcol) * KA
                                       + ch * 16 + wkh * 8];
        *(bf16x8*)&sW[(size_t)i * 8] = v;
    }
    __syncthreads();

    const int sbase = strip * (2048 * NCH) + kh * 256 + col * 8;
    const float bv = MEAN ? 0.f : bias[o0 + col];
    float csum = 0.f;
    const int step = gridDim.x >> 1;

    for (int rt = blockIdx.x >> 1; rt < NT; rt += step) {
        const int r0 = rt * 128 + rquar * 32;
        const int ar = min(r0 + col, NN - 1);     // clamped load row
        f32x16 acc = {0.f,0.f,0.f,0.f,0.f,0.f,0.f,0.f,
                      0.f,0.f,0.f,0.f,0.f,0.f,0.f,0.f};
#pragma unroll
        for (int op = 0; op < 2; ++op) {
            const ushort* __restrict__ in = op ? inB : inA;
            const ushort* ab = in + (size_t)ar * KA + kh * 8;
            bf16x8 a[NCH];
#pragma unroll
            for (int ch = 0; ch < NCH; ++ch) a[ch] = *(const bf16x8*)(ab + ch * 16);
#pragma unroll
            for (int ch = 0; ch < NCH; ++ch) {
                bf16x8 wh = *(const bf16x8*)&sW[sbase + ((op * NCH + ch) * 2 + 0) * 512];
                acc = __builtin_amdgcn_mfma_f32_32x32x16_bf16(a[ch], wh, acc, 0, 0, 0);
                bf16x8 wl = *(const bf16x8*)&sW[sbase + ((op * NCH + ch) * 2 + 1) * 512];
                acc = __builtin_amdgcn_mfma_f32_32x32x16_bf16(a[ch], wl, acc, 0, 0, 0);
            }
        }
        if (r0 < NN) {                      // whole 32-row subtile valid or not
            if (!MEAN) {
                const int o = o0 + col;
                const int rb = r0 + 4 * kh;
#pragma unroll
                for (int reg = 0; reg < 16; reg += 2) {
                    int ra = rb + (reg & 3) + 8 * (reg >> 2);   // pair rows ra, ra+1
                    float v0 = acc[reg] + bv;
                    float v1 = acc[reg + 1] + bv;
                    if (RELU) { v0 = fmaxf(v0, 0.f); v1 = fmaxf(v1, 0.f); }
                    out[(size_t)ra * HIDD + o]       = (ushort)bf16_rne(v0);
                    out[(size_t)(ra + 1) * HIDD + o] = (ushort)bf16_rne(v1);
                    if (FP8OUT) {
                        unsigned w = __builtin_amdgcn_cvt_pk_fp8_f32(v0, v1, 0u, false);
                        out8[(size_t)ra * HIDD + o]       = (unsigned char)(w & 0xFF);
                        out8[(size_t)(ra + 1) * HIDD + o] = (unsigned char)((w >> 8) & 0xFF);
                    }
                }
            } else {
#pragma unroll
                for (int reg = 0; reg < 16; ++reg) csum += acc[reg];
            }
        }
    }

    if (MEAN) {
        csum += __shfl_xor(csum, 32);       // combine the two k-half row-subsets
        if (lane < 32) atomicAdd(&gsum[o0 + col], csum);
    }
}

// ---------------------------------------------------------------------------
// Heads: g = gsum/N + b3; logits = relu(g@Pw1.T+Pb1)@Pw2.T+Pb2; value likewise.
// ---------------------------------------------------------------------------
__global__ void heads_kernel(const float* __restrict__ gsum,
                             const float* __restrict__ b3,
                             const float* __restrict__ Pw1, const float* __restrict__ Pb1,
                             const float* __restrict__ Pw2, const float* __restrict__ Pb2,
                             const float* __restrict__ Vw1, const float* __restrict__ Vb1,
                             const float* __restrict__ Vw2, const float* __restrict__ Vb2,
                             float* __restrict__ out, float inv_n) {
    __shared__ float g[128], a1[128], v1[128];
    int t = threadIdx.x;
    if (t < 128) g[t] = gsum[t] * inv_n + b3[t];
    __syncthreads();
    if (t < 128) {
        float s = Pb1[t];
        for (int f = 0; f < 128; ++f) s = fmaf(Pw1[t * 128 + f], g[f], s);
        a1[t] = fmaxf(s, 0.f);
    } else {
        int o = t - 128;
        float s = Vb1[o];
        for (int f = 0; f < 128; ++f) s = fmaf(Vw1[o * 128 + f], g[f], s);
        v1[o] = fmaxf(s, 0.f);
    }
    __syncthreads();
    if (t < 6) {
        float s = Pb2[t];
        for (int f = 0; f < 128; ++f) s = fmaf(Pw2[t * 128 + f], a1[f], s);
        out[t] = s;
    }
    if (t == 6) {
        float s = Vb2[0];
        for (int f = 0; f < 128; ++f) s = fmaf(Vw2[f], v1[f], s);
        out[6] = s;
    }
}

// ---------------------------------------------------------------------------
extern "C" void kernel_launch(void* const* d_in, const int* in_sizes, int n_in,
                              void* d_out, int out_size, void* d_ws, size_t ws_size,
                              hipStream_t stream) {
    const float* x    = (const float*)d_in[0];
    const int*   edges = (const int*)d_in[1];
    const float* W1l = (const float*)d_in[2];
    const float* b1  = (const float*)d_in[3];
    const float* W1r = (const float*)d_in[4];
    const float* W2l = (const float*)d_in[5];
    const float* b2  = (const float*)d_in[6];
    const float* W2r = (const float*)d_in[7];
    const float* W3l = (const float*)d_in[8];
    const float* b3  = (const float*)d_in[9];
    const float* W3r = (const float*)d_in[10];
    const float* Pw1 = (const float*)d_in[11];
    const float* Pb1 = (const float*)d_in[12];
    const float* Pw2 = (const float*)d_in[13];
    const float* Pb2 = (const float*)d_in[14];
    const float* Vw1 = (const float*)d_in[15];
    const float* Vb1 = (const float*)d_in[16];
    const float* Vw2 = (const float*)d_in[17];
    const float* Vb2 = (const float*)d_in[18];
    float* outp = (float*)d_out;

    const int E = in_sizes[1] / 2;

    // ---- workspace layout (int offsets, regions 256B-aligned) ----
    int*   ws_i = (int*)d_ws;
    float* ws_f = (float*)d_ws;
    size_t o_bcnt = 0;                 // NBC ints  (zeroed)
    size_t o_bcur = 256;               // NBC ints  (zeroed)
    size_t o_gsum = 512;               // 128 f32   (zeroed)
    size_t o_bptr = 640;               // NBC+1
    size_t o_rowp = 896;               // NN+1
    size_t o_bed  = 100928;            // E packed bucket edges
    size_t o_col  = o_bed + (size_t)E;           // E
    size_t o_whi  = ((o_col + (size_t)E + 63) / 64) * 64;  // 73728 shorts = 36864 ints
    size_t o_wlo  = o_whi + 36864;
    size_t o_x16  = o_wlo + 36864;               // NN*32 bf16 = NN*16 ints
    size_t o_aggr = o_x16 + (size_t)NN * 16;     // NN*128 bf16 = NN*64 ints
    size_t o_hA   = o_aggr + (size_t)NN * 64;
    size_t o_hB   = o_hA + (size_t)NN * 64;
    size_t o_h8   = o_hB + (size_t)NN * 64;      // NN*128 fp8 = NN*32 ints

    int*    bcnt    = ws_i + o_bcnt;
    int*    bcur    = ws_i + o_bcur;
    float*  gsum    = ws_f + o_gsum;
    int*    bptr    = ws_i + o_bptr;
    int*    row_ptr = ws_i + o_rowp;
    int*    bedges  = ws_i + o_bed;
    int*    col_src = ws_i + o_col;
    short*  whi     = (short*)(ws_i + o_whi);
    short*  wlo     = (short*)(ws_i + o_wlo);
    ushort* x16     = (ushort*)(ws_i + o_x16);
    ushort* aggr    = (ushort*)(ws_i + o_aggr);
    ushort* hA      = (ushort*)(ws_i + o_hA);
    ushort* hB      = (ushort*)(ws_i + o_hB);
    unsigned char* h8 = (unsigned char*)(ws_i + o_h8);

    short* W1l_hi = whi + 0;     short* W1l_lo = wlo + 0;
    short* W1r_hi = whi + 4096;  short* W1r_lo = wlo + 4096;
    short* W2l_hi = whi + 8192;  short* W2l_lo = wlo + 8192;
    short* W2r_hi = whi + 24576; short* W2r_lo = wlo + 24576;
    short* W3l_hi = whi + 40960; short* W3l_lo = wlo + 40960;
    short* W3r_hi = whi + 57344; short* W3r_lo = wlo + 57344;

    // zero bcnt, bcur, gsum
    hipMemsetAsync(d_ws, 0, 640 * sizeof(int), stream);

    const int TB = 256;
    dim3 blk(TB);
    dim3 blk512(512);

    // independent prep
    to_bf16<<<(NN * 32 / 4 + TB - 1) / TB, blk, 0, stream>>>(x, x16, NN * 32);
    split_weights<<<(73728 + TB - 1) / TB, blk, 0, stream>>>(
        W1l, W1r, W2l, W2r, W3l, W3r, whi, wlo);

    // bucketed CSR build (coarse 512-node buckets)
    bucket_hist<<<256, blk, 0, stream>>>(edges, E, bcnt);
    scan_bptr<<<1, 256, 0, stream>>>(bcnt, bptr);
    bucket_scatter<<<(E + SCAT_CHUNK - 1) / SCAT_CHUNK, blk, 0, stream>>>(
        edges, E, bptr, bcur, bedges);
    bucket_csr512<<<NBC, blk, 0, stream>>>(bedges, bptr, row_ptr, col_src);

    dim3 grid_agg((size_t)NN * 64 / TB);   // 25000: one wave per node
    dim3 grid_g(512);                      // lockstep half-pairs, grid-stride

    // Layer 1 (K=32, relu): epilogue also writes fp8 hA for layer-2 gather
    aggregate32_bf16<<<grid_agg, blk, 0, stream>>>(x16, row_ptr, col_src, aggr, NN);
    gemm32<32, true, false, true><<<grid_g, blk512, 0, stream>>>(
        aggr, x16, W1l_hi, W1l_lo, W1r_hi, W1r_lo, b1, hA, h8, nullptr);

    // Layer 2 (K=128, relu): epilogue writes fp8 hB for layer-3 gather
    aggregate128_fp8<<<grid_agg, blk, 0, stream>>>(h8, row_ptr, col_src, aggr, NN);
    gemm32<128, true, false, true><<<grid_g, blk512, 0, stream>>>(
        aggr, hA, W2l_hi, W2l_lo, W2r_hi, W2r_lo, b2, hB, h8, nullptr);

    // Layer 3 (K=128, fused column-mean into gsum)
    aggregate128_fp8<<<grid_agg, blk, 0, stream>>>(h8, row_ptr, col_src, aggr, NN);
    gemm32<128, false, true, false><<<grid_g, blk512, 0, stream>>>(
        aggr, hB, W3l_hi, W3l_lo, W3r_hi, W3r_lo, b3, nullptr, nullptr, gsum);

    // Heads (b3 folded into global mean here)
    heads_kernel<<<1, 256, 0, stream>>>(gsum, b3, Pw1, Pb1, Pw2, Pb2,
                                        Vw1, Vb1, Vw2, Vb2, outp,
                                        1.0f / (float)NN);
}

// Round 21
// 299.402 us; speedup vs baseline: 1.4356x; 1.1751x over previous
//
#include <hip/hip_runtime.h>
#include <hip/hip_bf16.h>

#define NN   100000
#define HIDD 128
#define NBC  196          // ceil(NN/512) coarse buckets of 512 nodes

typedef __attribute__((ext_vector_type(8))) short bf16x8;
typedef __attribute__((ext_vector_type(2))) float f32x2;
typedef __attribute__((ext_vector_type(4))) float f32x4;
typedef __attribute__((ext_vector_type(16))) float f32x16;

// RNE fp32 -> bf16 bits
__device__ __forceinline__ short bf16_rne(float v) {
    unsigned u = __float_as_uint(v);
    unsigned r = (u + 0x7fffu + ((u >> 16) & 1u)) >> 16;
    return (short)r;
}
__device__ __forceinline__ float bf16_to_f32(short b) {
    return __uint_as_float(((unsigned)(unsigned short)b) << 16);
}
__device__ __forceinline__ float bf16u_to_f32(ushort b) {
    return __uint_as_float(((unsigned)b) << 16);
}
__device__ __forceinline__ f32x2 unpack2p(unsigned u) {
    f32x2 r;
    r[0] = __uint_as_float((u & 0xFFFFu) << 16);
    r[1] = __uint_as_float(u & 0xFFFF0000u);
    return r;
}
__device__ __forceinline__ unsigned pack2(float a, float b) {
    return ((unsigned)(unsigned short)bf16_rne(a)) |
           (((unsigned)(unsigned short)bf16_rne(b)) << 16);
}

// ---------------------------------------------------------------------------
// Bucketed CSR build. bucket = dst >> 9 (512 nodes per bucket).
// ---------------------------------------------------------------------------
__global__ __launch_bounds__(256)
void bucket_hist(const int* __restrict__ edges, int n_edges,
                 int* __restrict__ bcnt) {
    __shared__ int lh[NBC];
    for (int i = threadIdx.x; i < NBC; i += 256) lh[i] = 0;
    __syncthreads();
    int stride = gridDim.x * blockDim.x;
    for (int e = blockIdx.x * blockDim.x + threadIdx.x; e < n_edges; e += stride) {
        int d = edges[n_edges + e];
        if ((unsigned)d < NN) atomicAdd(&lh[d >> 9], 1);
    }
    __syncthreads();
    for (int i = threadIdx.x; i < NBC; i += 256)
        if (lh[i]) atomicAdd(&bcnt[i], lh[i]);
}

__global__ void scan_bptr(const int* __restrict__ bcnt, int* __restrict__ bptr) {
    __shared__ int lds[256];
    int t = threadIdx.x;
    lds[t] = (t < NBC) ? bcnt[t] : 0;
    __syncthreads();
    for (int off = 1; off < 256; off <<= 1) {
        int u = (t >= off) ? lds[t - off] : 0;
        __syncthreads();
        lds[t] += u;
        __syncthreads();
    }
    if (t < NBC) bptr[t + 1] = lds[t];
    if (t == 0) bptr[0] = 0;
}

// Scatter edges into bucket regions as packed (dst_local<<17 | src).
#define SCAT_CHUNK 4096
__global__ __launch_bounds__(256)
void bucket_scatter(const int* __restrict__ edges, int n_edges,
                    const int* __restrict__ bptr, int* __restrict__ bcur,
                    int* __restrict__ bedges) {
    __shared__ int lh[NBC];
    __shared__ int lbase[NBC];
    int t = threadIdx.x;
    int base = blockIdx.x * SCAT_CHUNK;
    for (int i = t; i < NBC; i += 256) lh[i] = 0;
    __syncthreads();
#pragma unroll
    for (int i = 0; i < SCAT_CHUNK / 256; ++i) {
        int e = base + i * 256 + t;
        if (e < n_edges) {
            int d = edges[n_edges + e];
            if ((unsigned)d < NN) atomicAdd(&lh[d >> 9], 1);
        }
    }
    __syncthreads();
    for (int i = t; i < NBC; i += 256) {
        int c = lh[i];
        lbase[i] = (c > 0) ? atomicAdd(&bcur[i], c) : 0;
        lh[i] = 0;   // reuse as cursor
    }
    __syncthreads();
#pragma unroll
    for (int i = 0; i < SCAT_CHUNK / 256; ++i) {
        int e = base + i * 256 + t;
        if (e < n_edges) {
            int s = edges[e];
            int d = edges[n_edges + e];
            if ((unsigned)d < NN && (unsigned)s < NN) {
                int b = d >> 9;
                int off = atomicAdd(&lh[b], 1);
                bedges[bptr[b] + lbase[b] + off] = ((d & 511) << 17) | s;
            }
        }
    }
}

// One block per 512-node bucket: count -> pairwise scan -> place.
__global__ __launch_bounds__(256)
void bucket_csr512(const int* __restrict__ bedges, const int* __restrict__ bptr,
                   int* __restrict__ row_ptr, int* __restrict__ col_src) {
    __shared__ int lcnt[512];
    __shared__ int lsum[256];
    __shared__ int lexcl[512];
    int b = blockIdx.x;
    int t = threadIdx.x;
    int beg = bptr[b], end = bptr[b + 1];
    lcnt[t] = 0; lcnt[t + 256] = 0;
    __syncthreads();
    for (int e = beg + t; e < end; e += 256)
        atomicAdd(&lcnt[bedges[e] >> 17], 1);
    __syncthreads();
    int a0 = lcnt[2 * t], a1 = lcnt[2 * t + 1];
    lsum[t] = a0 + a1;
    __syncthreads();
    for (int off = 1; off < 256; off <<= 1) {
        int u = (t >= off) ? lsum[t - off] : 0;
        __syncthreads();
        lsum[t] += u;
        __syncthreads();
    }
    int pairExcl = lsum[t] - (a0 + a1);     // exclusive prefix of element 2t
    lexcl[2 * t]     = pairExcl;
    lexcl[2 * t + 1] = pairExcl + a0;
    int node0 = b << 9;
    int n0 = node0 + 2 * t, n1 = node0 + 2 * t + 1;
    if (n0 < NN) row_ptr[n0] = beg + pairExcl;
    if (n1 < NN) row_ptr[n1] = beg + pairExcl + a0;
    lcnt[2 * t] = 0; lcnt[2 * t + 1] = 0;   // reuse as cursors
    if (b == NBC - 1 && t == 0) row_ptr[NN] = end;
    __syncthreads();
    for (int e = beg + t; e < end; e += 256) {
        int p = bedges[e];
        int dl = p >> 17, src = p & 0x1FFFF;
        int pos = atomicAdd(&lcnt[dl], 1);
        col_src[beg + lexcl[dl] + pos] = src;
    }
}

// ---------------------------------------------------------------------------
// fp32 -> bf16 conversion (x)
// ---------------------------------------------------------------------------
__global__ void to_bf16(const float* __restrict__ in, ushort* __restrict__ out, int n) {
    int i = (blockIdx.x * blockDim.x + threadIdx.x) * 4;
    if (i + 3 >= n) {
        for (int k = i; k < n; ++k) out[k] = (ushort)bf16_rne(in[k]);
        return;
    }
    float4 v = *(const float4*)&in[i];
    unsigned lo = pack2(v.x, v.y), hi = pack2(v.z, v.w);
    *(uint2*)&out[i] = make_uint2(lo, hi);
}

// ---------------------------------------------------------------------------
// fp8 pull-mode mean aggregation: one wave per node, row = 128B.
// ---------------------------------------------------------------------------
__device__ __forceinline__ void acc_fp8x8p(f32x2* s, uint2 u) {
    s[0] += __builtin_amdgcn_cvt_pk_f32_fp8(u.x, false);
    s[1] += __builtin_amdgcn_cvt_pk_f32_fp8(u.x, true);
    s[2] += __builtin_amdgcn_cvt_pk_f32_fp8(u.y, false);
    s[3] += __builtin_amdgcn_cvt_pk_f32_fp8(u.y, true);
}

__global__ void aggregate128_fp8(const unsigned char* __restrict__ h8,
                                 const int* __restrict__ row_ptr,
                                 const int* __restrict__ col_src,
                                 ushort* __restrict__ aggr16, int n_nodes) {
    int node = (int)((blockIdx.x * (size_t)blockDim.x + threadIdx.x) >> 6);
    int lane = threadIdx.x & 63;
    if (node >= n_nodes) return;
    const int g   = lane >> 4;        // neighbor group 0..3
    const int seg = lane & 15;        // 8B segment within 128B row
    int beg = row_ptr[node], end = row_ptr[node + 1];
    f32x2 s[4];
#pragma unroll
    for (int e = 0; e < 4; ++e) s[e] = (f32x2){0.f, 0.f};
    int j = beg;
    for (; j + 16 <= end; j += 16) {               // 4 batches in flight
        int i0 = col_src[j + g];
        int i1 = col_src[j + 4 + g];
        int i2 = col_src[j + 8 + g];
        int i3 = col_src[j + 12 + g];
        uint2 u0 = *(const uint2*)&h8[(size_t)i0 * HIDD + seg * 8];
        uint2 u1 = *(const uint2*)&h8[(size_t)i1 * HIDD + seg * 8];
        uint2 u2 = *(const uint2*)&h8[(size_t)i2 * HIDD + seg * 8];
        uint2 u3 = *(const uint2*)&h8[(size_t)i3 * HIDD + seg * 8];
        acc_fp8x8p(s, u0);
        acc_fp8x8p(s, u1);
        acc_fp8x8p(s, u2);
        acc_fp8x8p(s, u3);
    }
    for (; j + 8 <= end; j += 8) {                 // 2 batches in flight
        int i0 = col_src[j + g];
        int i1 = col_src[j + 4 + g];
        uint2 u0 = *(const uint2*)&h8[(size_t)i0 * HIDD + seg * 8];
        uint2 u1 = *(const uint2*)&h8[(size_t)i1 * HIDD + seg * 8];
        acc_fp8x8p(s, u0);
        acc_fp8x8p(s, u1);
    }
    for (; j + 4 <= end; j += 4) {
        int i0 = col_src[j + g];
        uint2 u0 = *(const uint2*)&h8[(size_t)i0 * HIDD + seg * 8];
        acc_fp8x8p(s, u0);
    }
    int rem = end - j;
    if (g < rem) {                                 // masked tail, one step
        int i0 = col_src[j + g];
        uint2 u0 = *(const uint2*)&h8[(size_t)i0 * HIDD + seg * 8];
        acc_fp8x8p(s, u0);
    }
    // reduce across the 4 groups
#pragma unroll
    for (int e = 0; e < 4; ++e) {
        s[e][0] += __shfl_xor(s[e][0], 16);
        s[e][1] += __shfl_xor(s[e][1], 16);
        s[e][0] += __shfl_xor(s[e][0], 32);
        s[e][1] += __shfl_xor(s[e][1], 32);
    }
    float inv = (end > beg) ? 1.0f / (float)(end - beg) : 0.0f;
    if (lane < 16) {
        unsigned r0 = pack2(s[0][0] * inv, s[0][1] * inv);
        unsigned r1 = pack2(s[1][0] * inv, s[1][1] * inv);
        unsigned r2 = pack2(s[2][0] * inv, s[2][1] * inv);
        unsigned r3 = pack2(s[3][0] * inv, s[3][1] * inv);
        *(uint4*)&aggr16[(size_t)node * HIDD + seg * 8] = make_uint4(r0, r1, r2, r3);
    }
}

// One wave per node; 4 lanes x 16B cover one 64B row; 16 groups =>
// 16 neighbors per load instruction. Packed f32x2 accumulation.
__global__ void aggregate32_bf16(const ushort* __restrict__ x16,
                                 const int* __restrict__ row_ptr,
                                 const int* __restrict__ col_src,
                                 ushort* __restrict__ aggr16, int n_nodes) {
    int node = (int)((blockIdx.x * (size_t)blockDim.x + threadIdx.x) >> 6);
    int lane = threadIdx.x & 63;
    if (node >= n_nodes) return;
    const int g   = lane >> 2;        // neighbor group 0..15
    const int seg = lane & 3;         // 16B segment within 64B row
    int beg = row_ptr[node], end = row_ptr[node + 1];
    f32x2 s[4];
#pragma unroll
    for (int e = 0; e < 4; ++e) s[e] = (f32x2){0.f, 0.f};
    int j = beg;
    for (; j + 16 <= end; j += 16) {
        int i0 = col_src[j + g];
        uint4 u = *(const uint4*)&x16[(size_t)i0 * 32 + seg * 8];
        s[0] += unpack2p(u.x);
        s[1] += unpack2p(u.y);
        s[2] += unpack2p(u.z);
        s[3] += unpack2p(u.w);
    }
    int rem = end - j;
    if (g < rem) {                                 // masked tail (up to 15)
        int i0 = col_src[j + g];
        uint4 u = *(const uint4*)&x16[(size_t)i0 * 32 + seg * 8];
        s[0] += unpack2p(u.x);
        s[1] += unpack2p(u.y);
        s[2] += unpack2p(u.z);
        s[3] += unpack2p(u.w);
    }
    // reduce across the 16 groups
#pragma unroll
    for (int e = 0; e < 4; ++e) {
#pragma unroll
        for (int h = 0; h < 2; ++h) {
            s[e][h] += __shfl_xor(s[e][h], 4);
            s[e][h] += __shfl_xor(s[e][h], 8);
            s[e][h] += __shfl_xor(s[e][h], 16);
            s[e][h] += __shfl_xor(s[e][h], 32);
        }
    }
    float inv = (end > beg) ? 1.0f / (float)(end - beg) : 0.0f;
    if (lane < 4) {
        unsigned r0 = pack2(s[0][0] * inv, s[0][1] * inv);
        unsigned r1 = pack2(s[1][0] * inv, s[1][1] * inv);
        unsigned r2 = pack2(s[2][0] * inv, s[2][1] * inv);
        unsigned r3 = pack2(s[3][0] * inv, s[3][1] * inv);
        *(uint4*)&aggr16[(size_t)node * 32 + seg * 8] = make_uint4(r0, r1, r2, r3);
    }
}

// ---------------------------------------------------------------------------
// Weight pre-split: fp32 -> (hi, lo) bf16 planes (lo kept for fallback but
// unused by the single-plane GEMM).
// ---------------------------------------------------------------------------
__global__ void split_weights(const float* __restrict__ W1l, const float* __restrict__ W1r,
                              const float* __restrict__ W2l, const float* __restrict__ W2r,
                              const float* __restrict__ W3l, const float* __restrict__ W3r,
                              short* __restrict__ whi, short* __restrict__ wlo) {
    int i = blockIdx.x * blockDim.x + threadIdx.x;
    if (i >= 73728) return;
    const float* src; int off;
    if (i < 4096)       { src = W1l; off = 0; }
    else if (i < 8192)  { src = W1r; off = 4096; }
    else if (i < 24576) { src = W2l; off = 8192; }
    else if (i < 40960) { src = W2r; off = 24576; }
    else if (i < 57344) { src = W3l; off = 40960; }
    else                { src = W3r; off = 57344; }
    float v = src[i - off];
    short h = bf16_rne(v);
    float l = v - bf16_to_f32(h);
    whi[i] = h;
    wlo[i] = bf16_rne(l);
}

// ---------------------------------------------------------------------------
// 32x32x16-MFMA dual GEMM — v6: r16 geometry, SINGLE bf16 W plane.
// r17-r20 schedule perturbations all regressed vs r16; this keeps r16's
// exact schedule (256 thr = 4 waves, 64-row tiles, grid 512 lockstep pairs)
// and halves the work instead: no lo-plane => 16 MFMA + 16 ds_read per tile,
// LDS 32KB -> 5 blocks/CU (launch_bounds(256,5)) = 5 waves/SIMD.
// Precision: bf16 weights add ~1e-3/layer; with fp8 gather total ~2-3e-3,
// threshold 1.07e-2 (revert to dual-plane if absmax fails).
// FP8OUT: epilogue also emits fp8 e4m3 copy for the next layer's gather.
// ---------------------------------------------------------------------------
template <int KA, bool RELU, bool MEAN, bool FP8OUT>
__global__ __launch_bounds__(256, 5)
void gemm32(const ushort* __restrict__ inA, const ushort* __restrict__ inB,
            const short* __restrict__ WAhi, const short* __restrict__ WBhi,
            const float* __restrict__ bias,
            ushort* __restrict__ out, unsigned char* __restrict__ out8,
            float* __restrict__ gsum) {
    constexpr int NCH = KA / 16;            // k-chunks of 16
    constexpr int NT  = (NN + 63) / 64;     // 1563 tiles of 64 rows
    __shared__ __align__(16) ushort sW[2048 * NCH];  // 32KB at KA=128

    const int t = threadIdx.x;
    const int wave = t >> 6, lane = t & 63;
    const int half  = blockIdx.x & 1;
    const int strip = wave & 1;             // 32-col strip within the half
    const int rhalf = wave >> 1;            // 32-row half of the 64-row tile
    const int col = lane & 31;
    const int kh  = lane >> 5;              // k-half of the fragment
    const int o0 = half * 64 + strip * 32;

    // ---- stage W (hi only, both ops) for this 64-col half; frag-linear ----
    // frag f = st*(2*NCH) + op*NCH + ch, 512 ushorts each, offset wkh*256+wcol*8
    for (int i = t; i < 256 * NCH; i += 256) {
        int f = i >> 6;
        int w = i & 63;
        int wkh = w >> 5, wcol = w & 31;
        int st = f / (2 * NCH);
        int rem = f % (2 * NCH);
        int op = rem / NCH;
        int ch = rem % NCH;
        const short* Wp = op ? WBhi : WAhi;
        bf16x8 v = *(const bf16x8*)&Wp[(size_t)(half * 64 + st * 32 + wcol) * KA
                                       + ch * 16 + wkh * 8];
        *(bf16x8*)&sW[(size_t)i * 8] = v;
    }
    __syncthreads();

    const int sbase = strip * (1024 * NCH) + kh * 256 + col * 8;
    const float bv = MEAN ? 0.f : bias[o0 + col];
    float csum = 0.f;
    const int step = gridDim.x >> 1;

    for (int rt = blockIdx.x >> 1; rt < NT; rt += step) {
        const int r0 = rt * 64 + rhalf * 32;
        const int ar = min(r0 + col, NN - 1);     // clamped load row
        f32x16 acc = {0.f,0.f,0.f,0.f,0.f,0.f,0.f,0.f,
                      0.f,0.f,0.f,0.f,0.f,0.f,0.f,0.f};
#pragma unroll
        for (int op = 0; op < 2; ++op) {
            const ushort* __restrict__ in = op ? inB : inA;
            const ushort* ab = in + (size_t)ar * KA + kh * 8;
            bf16x8 a[NCH];
#pragma unroll
            for (int ch = 0; ch < NCH; ++ch) a[ch] = *(const bf16x8*)(ab + ch * 16);
#pragma unroll
            for (int ch = 0; ch < NCH; ++ch) {
                bf16x8 wh = *(const bf16x8*)&sW[sbase + (op * NCH + ch) * 512];
                acc = __builtin_amdgcn_mfma_f32_32x32x16_bf16(a[ch], wh, acc, 0, 0, 0);
            }
        }
        if (r0 < NN) {                      // whole 32-row subtile valid or not
            if (!MEAN) {
                const int o = o0 + col;
                const int rb = r0 + 4 * kh;
#pragma unroll
                for (int reg = 0; reg < 16; reg += 2) {
                    int ra = rb + (reg & 3) + 8 * (reg >> 2);   // pair rows ra, ra+1
                    float v0 = acc[reg] + bv;
                    float v1 = acc[reg + 1] + bv;
                    if (RELU) { v0 = fmaxf(v0, 0.f); v1 = fmaxf(v1, 0.f); }
                    out[(size_t)ra * HIDD + o]       = (ushort)bf16_rne(v0);
                    out[(size_t)(ra + 1) * HIDD + o] = (ushort)bf16_rne(v1);
                    if (FP8OUT) {
                        unsigned w = __builtin_amdgcn_cvt_pk_fp8_f32(v0, v1, 0u, false);
                        out8[(size_t)ra * HIDD + o]       = (unsigned char)(w & 0xFF);
                        out8[(size_t)(ra + 1) * HIDD + o] = (unsigned char)((w >> 8) & 0xFF);
                    }
                }
            } else {
#pragma unroll
                for (int reg = 0; reg < 16; ++reg) csum += acc[reg];
            }
        }
    }

    if (MEAN) {
        csum += __shfl_xor(csum, 32);       // combine the two k-half row-subsets
        if (lane < 32) atomicAdd(&gsum[o0 + col], csum);
    }
}

// ---------------------------------------------------------------------------
// Heads: g = gsum/N + b3; logits = relu(g@Pw1.T+Pb1)@Pw2.T+Pb2; value likewise.
// ---------------------------------------------------------------------------
__global__ void heads_kernel(const float* __restrict__ gsum,
                             const float* __restrict__ b3,
                             const float* __restrict__ Pw1, const float* __restrict__ Pb1,
                             const float* __restrict__ Pw2, const float* __restrict__ Pb2,
                             const float* __restrict__ Vw1, const float* __restrict__ Vb1,
                             const float* __restrict__ Vw2, const float* __restrict__ Vb2,
                             float* __restrict__ out, float inv_n) {
    __shared__ float g[128], a1[128], v1[128];
    int t = threadIdx.x;
    if (t < 128) g[t] = gsum[t] * inv_n + b3[t];
    __syncthreads();
    if (t < 128) {
        float s = Pb1[t];
        for (int f = 0; f < 128; ++f) s = fmaf(Pw1[t * 128 + f], g[f], s);
        a1[t] = fmaxf(s, 0.f);
    } else {
        int o = t - 128;
        float s = Vb1[o];
        for (int f = 0; f < 128; ++f) s = fmaf(Vw1[o * 128 + f], g[f], s);
        v1[o] = fmaxf(s, 0.f);
    }
    __syncthreads();
    if (t < 6) {
        float s = Pb2[t];
        for (int f = 0; f < 128; ++f) s = fmaf(Pw2[t * 128 + f], a1[f], s);
        out[t] = s;
    }
    if (t == 6) {
        float s = Vb2[0];
        for (int f = 0; f < 128; ++f) s = fmaf(Vw2[f], v1[f], s);
        out[6] = s;
    }
}

// ---------------------------------------------------------------------------
extern "C" void kernel_launch(void* const* d_in, const int* in_sizes, int n_in,
                              void* d_out, int out_size, void* d_ws, size_t ws_size,
                              hipStream_t stream) {
    const float* x    = (const float*)d_in[0];
    const int*   edges = (const int*)d_in[1];
    const float* W1l = (const float*)d_in[2];
    const float* b1  = (const float*)d_in[3];
    const float* W1r = (const float*)d_in[4];
    const float* W2l = (const float*)d_in[5];
    const float* b2  = (const float*)d_in[6];
    const float* W2r = (const float*)d_in[7];
    const float* W3l = (const float*)d_in[8];
    const float* b3  = (const float*)d_in[9];
    const float* W3r = (const float*)d_in[10];
    const float* Pw1 = (const float*)d_in[11];
    const float* Pb1 = (const float*)d_in[12];
    const float* Pw2 = (const float*)d_in[13];
    const float* Pb2 = (const float*)d_in[14];
    const float* Vw1 = (const float*)d_in[15];
    const float* Vb1 = (const float*)d_in[16];
    const float* Vw2 = (const float*)d_in[17];
    const float* Vb2 = (const float*)d_in[18];
    float* outp = (float*)d_out;

    const int E = in_sizes[1] / 2;

    // ---- workspace layout (int offsets, regions 256B-aligned) ----
    int*   ws_i = (int*)d_ws;
    float* ws_f = (float*)d_ws;
    size_t o_bcnt = 0;                 // NBC ints  (zeroed)
    size_t o_bcur = 256;               // NBC ints  (zeroed)
    size_t o_gsum = 512;               // 128 f32   (zeroed)
    size_t o_bptr = 640;               // NBC+1
    size_t o_rowp = 896;               // NN+1
    size_t o_bed  = 100928;            // E packed bucket edges
    size_t o_col  = o_bed + (size_t)E;           // E
    size_t o_whi  = ((o_col + (size_t)E + 63) / 64) * 64;  // 73728 shorts = 36864 ints
    size_t o_wlo  = o_whi + 36864;
    size_t o_x16  = o_wlo + 36864;               // NN*32 bf16 = NN*16 ints
    size_t o_aggr = o_x16 + (size_t)NN * 16;     // NN*128 bf16 = NN*64 ints
    size_t o_hA   = o_aggr + (size_t)NN * 64;
    size_t o_hB   = o_hA + (size_t)NN * 64;
    size_t o_h8   = o_hB + (size_t)NN * 64;      // NN*128 fp8 = NN*32 ints

    int*    bcnt    = ws_i + o_bcnt;
    int*    bcur    = ws_i + o_bcur;
    float*  gsum    = ws_f + o_gsum;
    int*    bptr    = ws_i + o_bptr;
    int*    row_ptr = ws_i + o_rowp;
    int*    bedges  = ws_i + o_bed;
    int*    col_src = ws_i + o_col;
    short*  whi     = (short*)(ws_i + o_whi);
    short*  wlo     = (short*)(ws_i + o_wlo);
    ushort* x16     = (ushort*)(ws_i + o_x16);
    ushort* aggr    = (ushort*)(ws_i + o_aggr);
    ushort* hA      = (ushort*)(ws_i + o_hA);
    ushort* hB      = (ushort*)(ws_i + o_hB);
    unsigned char* h8 = (unsigned char*)(ws_i + o_h8);

    short* W1l_hi = whi + 0;
    short* W1r_hi = whi + 4096;
    short* W2l_hi = whi + 8192;
    short* W2r_hi = whi + 24576;
    short* W3l_hi = whi + 40960;
    short* W3r_hi = whi + 57344;

    // zero bcnt, bcur, gsum
    hipMemsetAsync(d_ws, 0, 640 * sizeof(int), stream);

    const int TB = 256;
    dim3 blk(TB);

    // independent prep
    to_bf16<<<(NN * 32 / 4 + TB - 1) / TB, blk, 0, stream>>>(x, x16, NN * 32);
    split_weights<<<(73728 + TB - 1) / TB, blk, 0, stream>>>(
        W1l, W1r, W2l, W2r, W3l, W3r, whi, wlo);

    // bucketed CSR build (coarse 512-node buckets)
    bucket_hist<<<256, blk, 0, stream>>>(edges, E, bcnt);
    scan_bptr<<<1, 256, 0, stream>>>(bcnt, bptr);
    bucket_scatter<<<(E + SCAT_CHUNK - 1) / SCAT_CHUNK, blk, 0, stream>>>(
        edges, E, bptr, bcur, bedges);
    bucket_csr512<<<NBC, blk, 0, stream>>>(bedges, bptr, row_ptr, col_src);

    dim3 grid_agg((size_t)NN * 64 / TB);   // 25000: one wave per node
    dim3 grid_g(512);                      // lockstep half-pairs, grid-stride

    // Layer 1 (K=32, relu): epilogue also writes fp8 hA for layer-2 gather
    aggregate32_bf16<<<grid_agg, blk, 0, stream>>>(x16, row_ptr, col_src, aggr, NN);
    gemm32<32, true, false, true><<<grid_g, blk, 0, stream>>>(
        aggr, x16, W1l_hi, W1r_hi, b1, hA, h8, nullptr);

    // Layer 2 (K=128, relu): epilogue writes fp8 hB for layer-3 gather
    aggregate128_fp8<<<grid_agg, blk, 0, stream>>>(h8, row_ptr, col_src, aggr, NN);
    gemm32<128, true, false, true><<<grid_g, blk, 0, stream>>>(
        aggr, hA, W2l_hi, W2r_hi, b2, hB, h8, nullptr);

    // Layer 3 (K=128, fused column-mean into gsum)
    aggregate128_fp8<<<grid_agg, blk, 0, stream>>>(h8, row_ptr, col_src, aggr, NN);
    gemm32<128, false, true, false><<<grid_g, blk, 0, stream>>>(
        aggr, hB, W3l_hi, W3r_hi, b3, nullptr, nullptr, gsum);

    // Heads (b3 folded into global mean here)
    heads_kernel<<<1, 256, 0, stream>>>(gsum, b3, Pw1, Pb1, Pw2, Pb2,
                                        Vw1, Vb1, Vw2, Vb2, outp,
                                        1.0f / (float)NN);
}

// Round 22
// 298.865 us; speedup vs baseline: 1.4382x; 1.0018x over previous
//
#include <hip/hip_runtime.h>
#include <hip/hip_bf16.h>

#define NN   100000
#define HIDD 128
#define NBC  196          // ceil(NN/512) coarse buckets of 512 nodes

typedef __attribute__((ext_vector_type(8))) short bf16x8;
typedef __attribute__((ext_vector_type(2))) float f32x2;
typedef __attribute__((ext_vector_type(4))) float f32x4;
typedef __attribute__((ext_vector_type(16))) float f32x16;

// RNE fp32 -> bf16 bits
__device__ __forceinline__ short bf16_rne(float v) {
    unsigned u = __float_as_uint(v);
    unsigned r = (u + 0x7fffu + ((u >> 16) & 1u)) >> 16;
    return (short)r;
}
__device__ __forceinline__ float bf16_to_f32(short b) {
    return __uint_as_float(((unsigned)(unsigned short)b) << 16);
}
__device__ __forceinline__ float bf16u_to_f32(ushort b) {
    return __uint_as_float(((unsigned)b) << 16);
}
__device__ __forceinline__ f32x2 unpack2p(unsigned u) {
    f32x2 r;
    r[0] = __uint_as_float((u & 0xFFFFu) << 16);
    r[1] = __uint_as_float(u & 0xFFFF0000u);
    return r;
}
__device__ __forceinline__ unsigned pack2(float a, float b) {
    return ((unsigned)(unsigned short)bf16_rne(a)) |
           (((unsigned)(unsigned short)bf16_rne(b)) << 16);
}

// ---------------------------------------------------------------------------
// Bucketed CSR build. bucket = dst >> 9 (512 nodes per bucket).
// col_src stores src<<7 = byte offset of the fp8 row (aggregates use it
// directly; the bf16/x16 row offset is (off>>1)).
// ---------------------------------------------------------------------------
__global__ __launch_bounds__(256)
void bucket_hist(const int* __restrict__ edges, int n_edges,
                 int* __restrict__ bcnt) {
    __shared__ int lh[NBC];
    for (int i = threadIdx.x; i < NBC; i += 256) lh[i] = 0;
    __syncthreads();
    int stride = gridDim.x * blockDim.x;
    for (int e = blockIdx.x * blockDim.x + threadIdx.x; e < n_edges; e += stride) {
        int d = edges[n_edges + e];
        if ((unsigned)d < NN) atomicAdd(&lh[d >> 9], 1);
    }
    __syncthreads();
    for (int i = threadIdx.x; i < NBC; i += 256)
        if (lh[i]) atomicAdd(&bcnt[i], lh[i]);
}

__global__ void scan_bptr(const int* __restrict__ bcnt, int* __restrict__ bptr) {
    __shared__ int lds[256];
    int t = threadIdx.x;
    lds[t] = (t < NBC) ? bcnt[t] : 0;
    __syncthreads();
    for (int off = 1; off < 256; off <<= 1) {
        int u = (t >= off) ? lds[t - off] : 0;
        __syncthreads();
        lds[t] += u;
        __syncthreads();
    }
    if (t < NBC) bptr[t + 1] = lds[t];
    if (t == 0) bptr[0] = 0;
}

// Scatter edges into bucket regions as packed (dst_local<<17 | src).
#define SCAT_CHUNK 4096
__global__ __launch_bounds__(256)
void bucket_scatter(const int* __restrict__ edges, int n_edges,
                    const int* __restrict__ bptr, int* __restrict__ bcur,
                    int* __restrict__ bedges) {
    __shared__ int lh[NBC];
    __shared__ int lbase[NBC];
    int t = threadIdx.x;
    int base = blockIdx.x * SCAT_CHUNK;
    for (int i = t; i < NBC; i += 256) lh[i] = 0;
    __syncthreads();
#pragma unroll
    for (int i = 0; i < SCAT_CHUNK / 256; ++i) {
        int e = base + i * 256 + t;
        if (e < n_edges) {
            int d = edges[n_edges + e];
            if ((unsigned)d < NN) atomicAdd(&lh[d >> 9], 1);
        }
    }
    __syncthreads();
    for (int i = t; i < NBC; i += 256) {
        int c = lh[i];
        lbase[i] = (c > 0) ? atomicAdd(&bcur[i], c) : 0;
        lh[i] = 0;   // reuse as cursor
    }
    __syncthreads();
#pragma unroll
    for (int i = 0; i < SCAT_CHUNK / 256; ++i) {
        int e = base + i * 256 + t;
        if (e < n_edges) {
            int s = edges[e];
            int d = edges[n_edges + e];
            if ((unsigned)d < NN && (unsigned)s < NN) {
                int b = d >> 9;
                int off = atomicAdd(&lh[b], 1);
                bedges[bptr[b] + lbase[b] + off] = ((d & 511) << 17) | s;
            }
        }
    }
}

// One block per 512-node bucket: count -> pairwise scan -> place.
__global__ __launch_bounds__(256)
void bucket_csr512(const int* __restrict__ bedges, const int* __restrict__ bptr,
                   int* __restrict__ row_ptr, int* __restrict__ col_src) {
    __shared__ int lcnt[512];
    __shared__ int lsum[256];
    __shared__ int lexcl[512];
    int b = blockIdx.x;
    int t = threadIdx.x;
    int beg = bptr[b], end = bptr[b + 1];
    lcnt[t] = 0; lcnt[t + 256] = 0;
    __syncthreads();
    for (int e = beg + t; e < end; e += 256)
        atomicAdd(&lcnt[bedges[e] >> 17], 1);
    __syncthreads();
    int a0 = lcnt[2 * t], a1 = lcnt[2 * t + 1];
    lsum[t] = a0 + a1;
    __syncthreads();
    for (int off = 1; off < 256; off <<= 1) {
        int u = (t >= off) ? lsum[t - off] : 0;
        __syncthreads();
        lsum[t] += u;
        __syncthreads();
    }
    int pairExcl = lsum[t] - (a0 + a1);     // exclusive prefix of element 2t
    lexcl[2 * t]     = pairExcl;
    lexcl[2 * t + 1] = pairExcl + a0;
    int node0 = b << 9;
    int n0 = node0 + 2 * t, n1 = node0 + 2 * t + 1;
    if (n0 < NN) row_ptr[n0] = beg + pairExcl;
    if (n1 < NN) row_ptr[n1] = beg + pairExcl + a0;
    lcnt[2 * t] = 0; lcnt[2 * t + 1] = 0;   // reuse as cursors
    if (b == NBC - 1 && t == 0) row_ptr[NN] = end;
    __syncthreads();
    for (int e = beg + t; e < end; e += 256) {
        int p = bedges[e];
        int dl = p >> 17, src = p & 0x1FFFF;
        int pos = atomicAdd(&lcnt[dl], 1);
        col_src[beg + lexcl[dl] + pos] = src << 7;   // fp8-row byte offset
    }
}

// ---------------------------------------------------------------------------
// fp32 -> bf16 conversion (x)
// ---------------------------------------------------------------------------
__global__ void to_bf16(const float* __restrict__ in, ushort* __restrict__ out, int n) {
    int i = (blockIdx.x * blockDim.x + threadIdx.x) * 4;
    if (i + 3 >= n) {
        for (int k = i; k < n; ++k) out[k] = (ushort)bf16_rne(in[k]);
        return;
    }
    float4 v = *(const float4*)&in[i];
    unsigned lo = pack2(v.x, v.y), hi = pack2(v.z, v.w);
    *(uint2*)&out[i] = make_uint2(lo, hi);
}

// ---------------------------------------------------------------------------
// fp8 pull-mode mean aggregation: one wave per node, row = 128B.
// col_src holds byte offsets => address = base + off (no shift/mul).
// ---------------------------------------------------------------------------
__device__ __forceinline__ void acc_fp8x8p(f32x2* s, uint2 u) {
    s[0] += __builtin_amdgcn_cvt_pk_f32_fp8(u.x, false);
    s[1] += __builtin_amdgcn_cvt_pk_f32_fp8(u.x, true);
    s[2] += __builtin_amdgcn_cvt_pk_f32_fp8(u.y, false);
    s[3] += __builtin_amdgcn_cvt_pk_f32_fp8(u.y, true);
}

__global__ void aggregate128_fp8(const unsigned char* __restrict__ h8,
                                 const int* __restrict__ row_ptr,
                                 const int* __restrict__ col_src,
                                 ushort* __restrict__ aggr16, int n_nodes) {
    int node = (int)((blockIdx.x * (size_t)blockDim.x + threadIdx.x) >> 6);
    int lane = threadIdx.x & 63;
    if (node >= n_nodes) return;
    const int g   = lane >> 4;        // neighbor group 0..3
    const int seg = lane & 15;        // 8B segment within 128B row
    const unsigned char* hb = h8 + seg * 8;
    int beg = row_ptr[node], end = row_ptr[node + 1];
    f32x2 s[4];
#pragma unroll
    for (int e = 0; e < 4; ++e) s[e] = (f32x2){0.f, 0.f};
    int j = beg;
    for (; j + 16 <= end; j += 16) {               // 4 batches in flight
        int o0 = col_src[j + g];
        int o1 = col_src[j + 4 + g];
        int o2 = col_src[j + 8 + g];
        int o3 = col_src[j + 12 + g];
        uint2 u0 = *(const uint2*)(hb + o0);
        uint2 u1 = *(const uint2*)(hb + o1);
        uint2 u2 = *(const uint2*)(hb + o2);
        uint2 u3 = *(const uint2*)(hb + o3);
        acc_fp8x8p(s, u0);
        acc_fp8x8p(s, u1);
        acc_fp8x8p(s, u2);
        acc_fp8x8p(s, u3);
    }
    for (; j + 8 <= end; j += 8) {                 // 2 batches in flight
        int o0 = col_src[j + g];
        int o1 = col_src[j + 4 + g];
        uint2 u0 = *(const uint2*)(hb + o0);
        uint2 u1 = *(const uint2*)(hb + o1);
        acc_fp8x8p(s, u0);
        acc_fp8x8p(s, u1);
    }
    for (; j + 4 <= end; j += 4) {
        int o0 = col_src[j + g];
        uint2 u0 = *(const uint2*)(hb + o0);
        acc_fp8x8p(s, u0);
    }
    int rem = end - j;
    if (g < rem) {                                 // masked tail, one step
        int o0 = col_src[j + g];
        uint2 u0 = *(const uint2*)(hb + o0);
        acc_fp8x8p(s, u0);
    }
    // reduce across the 4 groups
#pragma unroll
    for (int e = 0; e < 4; ++e) {
        s[e][0] += __shfl_xor(s[e][0], 16);
        s[e][1] += __shfl_xor(s[e][1], 16);
        s[e][0] += __shfl_xor(s[e][0], 32);
        s[e][1] += __shfl_xor(s[e][1], 32);
    }
    float inv = (end > beg) ? 1.0f / (float)(end - beg) : 0.0f;
    if (lane < 16) {
        unsigned r0 = pack2(s[0][0] * inv, s[0][1] * inv);
        unsigned r1 = pack2(s[1][0] * inv, s[1][1] * inv);
        unsigned r2 = pack2(s[2][0] * inv, s[2][1] * inv);
        unsigned r3 = pack2(s[3][0] * inv, s[3][1] * inv);
        *(uint4*)&aggr16[(size_t)node * HIDD + seg * 8] = make_uint4(r0, r1, r2, r3);
    }
}

// One wave per node; 4 lanes x 16B cover one 64B row; 16 groups =>
// 16 neighbors per load instruction. Packed f32x2 accumulation.
// x16 row byte offset = col_src >> 1.
__global__ void aggregate32_bf16(const ushort* __restrict__ x16,
                                 const int* __restrict__ row_ptr,
                                 const int* __restrict__ col_src,
                                 ushort* __restrict__ aggr16, int n_nodes) {
    int node = (int)((blockIdx.x * (size_t)blockDim.x + threadIdx.x) >> 6);
    int lane = threadIdx.x & 63;
    if (node >= n_nodes) return;
    const int g   = lane >> 2;        // neighbor group 0..15
    const int seg = lane & 3;         // 16B segment within 64B row
    const unsigned char* xb = (const unsigned char*)x16 + seg * 16;
    int beg = row_ptr[node], end = row_ptr[node + 1];
    f32x2 s[4];
#pragma unroll
    for (int e = 0; e < 4; ++e) s[e] = (f32x2){0.f, 0.f};
    int j = beg;
    for (; j + 16 <= end; j += 16) {
        int o0 = col_src[j + g] >> 1;
        uint4 u = *(const uint4*)(xb + o0);
        s[0] += unpack2p(u.x);
        s[1] += unpack2p(u.y);
        s[2] += unpack2p(u.z);
        s[3] += unpack2p(u.w);
    }
    int rem = end - j;
    if (g < rem) {                                 // masked tail (up to 15)
        int o0 = col_src[j + g] >> 1;
        uint4 u = *(const uint4*)(xb + o0);
        s[0] += unpack2p(u.x);
        s[1] += unpack2p(u.y);
        s[2] += unpack2p(u.z);
        s[3] += unpack2p(u.w);
    }
    // reduce across the 16 groups
#pragma unroll
    for (int e = 0; e < 4; ++e) {
#pragma unroll
        for (int h = 0; h < 2; ++h) {
            s[e][h] += __shfl_xor(s[e][h], 4);
            s[e][h] += __shfl_xor(s[e][h], 8);
            s[e][h] += __shfl_xor(s[e][h], 16);
            s[e][h] += __shfl_xor(s[e][h], 32);
        }
    }
    float inv = (end > beg) ? 1.0f / (float)(end - beg) : 0.0f;
    if (lane < 4) {
        unsigned r0 = pack2(s[0][0] * inv, s[0][1] * inv);
        unsigned r1 = pack2(s[1][0] * inv, s[1][1] * inv);
        unsigned r2 = pack2(s[2][0] * inv, s[2][1] * inv);
        unsigned r3 = pack2(s[3][0] * inv, s[3][1] * inv);
        *(uint4*)&aggr16[(size_t)node * 32 + seg * 8] = make_uint4(r0, r1, r2, r3);
    }
}

// ---------------------------------------------------------------------------
// Weight conversion: fp32 -> bf16 (single plane; lo-plane dropped in r21).
// ---------------------------------------------------------------------------
__global__ void split_weights(const float* __restrict__ W1l, const float* __restrict__ W1r,
                              const float* __restrict__ W2l, const float* __restrict__ W2r,
                              const float* __restrict__ W3l, const float* __restrict__ W3r,
                              short* __restrict__ whi) {
    int i = blockIdx.x * blockDim.x + threadIdx.x;
    if (i >= 73728) return;
    const float* src; int off;
    if (i < 4096)       { src = W1l; off = 0; }
    else if (i < 8192)  { src = W1r; off = 4096; }
    else if (i < 24576) { src = W2l; off = 8192; }
    else if (i < 40960) { src = W2r; off = 24576; }
    else if (i < 57344) { src = W3l; off = 40960; }
    else                { src = W3r; off = 57344; }
    whi[i] = bf16_rne(src[i - off]);
}

// ---------------------------------------------------------------------------
// 32x32x16-MFMA dual GEMM — r21 structure (best known): 256 thr = 4 waves,
// single bf16 W plane in 32KB LDS, 64-row tiles, grid 512 lockstep pairs,
// launch_bounds(256,5) -> 5 blocks/CU.
// FP8OUT: epilogue also emits fp8 e4m3 copy for the next layer's gather.
// ---------------------------------------------------------------------------
template <int KA, bool RELU, bool MEAN, bool FP8OUT>
__global__ __launch_bounds__(256, 5)
void gemm32(const ushort* __restrict__ inA, const ushort* __restrict__ inB,
            const short* __restrict__ WAhi, const short* __restrict__ WBhi,
            const float* __restrict__ bias,
            ushort* __restrict__ out, unsigned char* __restrict__ out8,
            float* __restrict__ gsum) {
    constexpr int NCH = KA / 16;            // k-chunks of 16
    constexpr int NT  = (NN + 63) / 64;     // 1563 tiles of 64 rows
    __shared__ __align__(16) ushort sW[2048 * NCH];  // 32KB at KA=128

    const int t = threadIdx.x;
    const int wave = t >> 6, lane = t & 63;
    const int half  = blockIdx.x & 1;
    const int strip = wave & 1;             // 32-col strip within the half
    const int rhalf = wave >> 1;            // 32-row half of the 64-row tile
    const int col = lane & 31;
    const int kh  = lane >> 5;              // k-half of the fragment
    const int o0 = half * 64 + strip * 32;

    // ---- stage W (hi only, both ops) for this 64-col half; frag-linear ----
    for (int i = t; i < 256 * NCH; i += 256) {
        int f = i >> 6;
        int w = i & 63;
        int wkh = w >> 5, wcol = w & 31;
        int st = f / (2 * NCH);
        int rem = f % (2 * NCH);
        int op = rem / NCH;
        int ch = rem % NCH;
        const short* Wp = op ? WBhi : WAhi;
        bf16x8 v = *(const bf16x8*)&Wp[(size_t)(half * 64 + st * 32 + wcol) * KA
                                       + ch * 16 + wkh * 8];
        *(bf16x8*)&sW[(size_t)i * 8] = v;
    }
    __syncthreads();

    const int sbase = strip * (1024 * NCH) + kh * 256 + col * 8;
    const float bv = MEAN ? 0.f : bias[o0 + col];
    float csum = 0.f;
    const int step = gridDim.x >> 1;

    for (int rt = blockIdx.x >> 1; rt < NT; rt += step) {
        const int r0 = rt * 64 + rhalf * 32;
        const int ar = min(r0 + col, NN - 1);     // clamped load row
        f32x16 acc = {0.f,0.f,0.f,0.f,0.f,0.f,0.f,0.f,
                      0.f,0.f,0.f,0.f,0.f,0.f,0.f,0.f};
#pragma unroll
        for (int op = 0; op < 2; ++op) {
            const ushort* __restrict__ in = op ? inB : inA;
            const ushort* ab = in + (size_t)ar * KA + kh * 8;
            bf16x8 a[NCH];
#pragma unroll
            for (int ch = 0; ch < NCH; ++ch) a[ch] = *(const bf16x8*)(ab + ch * 16);
#pragma unroll
            for (int ch = 0; ch < NCH; ++ch) {
                bf16x8 wh = *(const bf16x8*)&sW[sbase + (op * NCH + ch) * 512];
                acc = __builtin_amdgcn_mfma_f32_32x32x16_bf16(a[ch], wh, acc, 0, 0, 0);
            }
        }
        if (r0 < NN) {                      // whole 32-row subtile valid or not
            if (!MEAN) {
                const int o = o0 + col;
                const int rb = r0 + 4 * kh;
#pragma unroll
                for (int reg = 0; reg < 16; reg += 2) {
                    int ra = rb + (reg & 3) + 8 * (reg >> 2);   // pair rows ra, ra+1
                    float v0 = acc[reg] + bv;
                    float v1 = acc[reg + 1] + bv;
                    if (RELU) { v0 = fmaxf(v0, 0.f); v1 = fmaxf(v1, 0.f); }
                    out[(size_t)ra * HIDD + o]       = (ushort)bf16_rne(v0);
                    out[(size_t)(ra + 1) * HIDD + o] = (ushort)bf16_rne(v1);
                    if (FP8OUT) {
                        unsigned w = __builtin_amdgcn_cvt_pk_fp8_f32(v0, v1, 0u, false);
                        out8[(size_t)ra * HIDD + o]       = (unsigned char)(w & 0xFF);
                        out8[(size_t)(ra + 1) * HIDD + o] = (unsigned char)((w >> 8) & 0xFF);
                    }
                }
            } else {
#pragma unroll
                for (int reg = 0; reg < 16; ++reg) csum += acc[reg];
            }
        }
    }

    if (MEAN) {
        csum += __shfl_xor(csum, 32);       // combine the two k-half row-subsets
        if (lane < 32) atomicAdd(&gsum[o0 + col], csum);
    }
}

// ---------------------------------------------------------------------------
// Heads: g = gsum/N + b3; logits = relu(g@Pw1.T+Pb1)@Pw2.T+Pb2; value likewise.
// ---------------------------------------------------------------------------
__global__ void heads_kernel(const float* __restrict__ gsum,
                             const float* __restrict__ b3,
                             const float* __restrict__ Pw1, const float* __restrict__ Pb1,
                             const float* __restrict__ Pw2, const float* __restrict__ Pb2,
                             const float* __restrict__ Vw1, const float* __restrict__ Vb1,
                             const float* __restrict__ Vw2, const float* __restrict__ Vb2,
                             float* __restrict__ out, float inv_n) {
    __shared__ float g[128], a1[128], v1[128];
    int t = threadIdx.x;
    if (t < 128) g[t] = gsum[t] * inv_n + b3[t];
    __syncthreads();
    if (t < 128) {
        float s = Pb1[t];
        for (int f = 0; f < 128; ++f) s = fmaf(Pw1[t * 128 + f], g[f], s);
        a1[t] = fmaxf(s, 0.f);
    } else {
        int o = t - 128;
        float s = Vb1[o];
        for (int f = 0; f < 128; ++f) s = fmaf(Vw1[o * 128 + f], g[f], s);
        v1[o] = fmaxf(s, 0.f);
    }
    __syncthreads();
    if (t < 6) {
        float s = Pb2[t];
        for (int f = 0; f < 128; ++f) s = fmaf(Pw2[t * 128 + f], a1[f], s);
        out[t] = s;
    }
    if (t == 6) {
        float s = Vb2[0];
        for (int f = 0; f < 128; ++f) s = fmaf(Vw2[f], v1[f], s);
        out[6] = s;
    }
}

// ---------------------------------------------------------------------------
extern "C" void kernel_launch(void* const* d_in, const int* in_sizes, int n_in,
                              void* d_out, int out_size, void* d_ws, size_t ws_size,
                              hipStream_t stream) {
    const float* x    = (const float*)d_in[0];
    const int*   edges = (const int*)d_in[1];
    const float* W1l = (const float*)d_in[2];
    const float* b1  = (const float*)d_in[3];
    const float* W1r = (const float*)d_in[4];
    const float* W2l = (const float*)d_in[5];
    const float* b2  = (const float*)d_in[6];
    const float* W2r = (const float*)d_in[7];
    const float* W3l = (const float*)d_in[8];
    const float* b3  = (const float*)d_in[9];
    const float* W3r = (const float*)d_in[10];
    const float* Pw1 = (const float*)d_in[11];
    const float* Pb1 = (const float*)d_in[12];
    const float* Pw2 = (const float*)d_in[13];
    const float* Pb2 = (const float*)d_in[14];
    const float* Vw1 = (const float*)d_in[15];
    const float* Vb1 = (const float*)d_in[16];
    const float* Vw2 = (const float*)d_in[17];
    const float* Vb2 = (const float*)d_in[18];
    float* outp = (float*)d_out;

    const int E = in_sizes[1] / 2;

    // ---- workspace layout (int offsets, regions 256B-aligned) ----
    int*   ws_i = (int*)d_ws;
    float* ws_f = (float*)d_ws;
    size_t o_bcnt = 0;                 // NBC ints  (zeroed)
    size_t o_bcur = 256;               // NBC ints  (zeroed)
    size_t o_gsum = 512;               // 128 f32   (zeroed)
    size_t o_bptr = 640;               // NBC+1
    size_t o_rowp = 896;               // NN+1
    size_t o_bed  = 100928;            // E packed bucket edges
    size_t o_col  = o_bed + (size_t)E;           // E
    size_t o_whi  = ((o_col + (size_t)E + 63) / 64) * 64;  // 73728 shorts = 36864 ints
    size_t o_x16  = o_whi + 36864;               // NN*32 bf16 = NN*16 ints
    size_t o_aggr = o_x16 + (size_t)NN * 16;     // NN*128 bf16 = NN*64 ints
    size_t o_hA   = o_aggr + (size_t)NN * 64;
    size_t o_hB   = o_hA + (size_t)NN * 64;
    size_t o_h8   = o_hB + (size_t)NN * 64;      // NN*128 fp8 = NN*32 ints

    int*    bcnt    = ws_i + o_bcnt;
    int*    bcur    = ws_i + o_bcur;
    float*  gsum    = ws_f + o_gsum;
    int*    bptr    = ws_i + o_bptr;
    int*    row_ptr = ws_i + o_rowp;
    int*    bedges  = ws_i + o_bed;
    int*    col_src = ws_i + o_col;
    short*  whi     = (short*)(ws_i + o_whi);
    ushort* x16     = (ushort*)(ws_i + o_x16);
    ushort* aggr    = (ushort*)(ws_i + o_aggr);
    ushort* hA      = (ushort*)(ws_i + o_hA);
    ushort* hB      = (ushort*)(ws_i + o_hB);
    unsigned char* h8 = (unsigned char*)(ws_i + o_h8);

    short* W1l_hi = whi + 0;
    short* W1r_hi = whi + 4096;
    short* W2l_hi = whi + 8192;
    short* W2r_hi = whi + 24576;
    short* W3l_hi = whi + 40960;
    short* W3r_hi = whi + 57344;

    // zero bcnt, bcur, gsum
    hipMemsetAsync(d_ws, 0, 640 * sizeof(int), stream);

    const int TB = 256;
    dim3 blk(TB);

    // independent prep
    to_bf16<<<(NN * 32 / 4 + TB - 1) / TB, blk, 0, stream>>>(x, x16, NN * 32);
    split_weights<<<(73728 + TB - 1) / TB, blk, 0, stream>>>(
        W1l, W1r, W2l, W2r, W3l, W3r, whi);

    // bucketed CSR build (coarse 512-node buckets)
    bucket_hist<<<256, blk, 0, stream>>>(edges, E, bcnt);
    scan_bptr<<<1, 256, 0, stream>>>(bcnt, bptr);
    bucket_scatter<<<(E + SCAT_CHUNK - 1) / SCAT_CHUNK, blk, 0, stream>>>(
        edges, E, bptr, bcur, bedges);
    bucket_csr512<<<NBC, blk, 0, stream>>>(bedges, bptr, row_ptr, col_src);

    dim3 grid_agg((size_t)NN * 64 / TB);   // 25000: one wave per node
    dim3 grid_g(512);                      // lockstep half-pairs, grid-stride

    // Layer 1 (K=32, relu): epilogue also writes fp8 hA for layer-2 gather
    aggregate32_bf16<<<grid_agg, blk, 0, stream>>>(x16, row_ptr, col_src, aggr, NN);
    gemm32<32, true, false, true><<<grid_g, blk, 0, stream>>>(
        aggr, x16, W1l_hi, W1r_hi, b1, hA, h8, nullptr);

    // Layer 2 (K=128, relu): epilogue writes fp8 hB for layer-3 gather
    aggregate128_fp8<<<grid_agg, blk, 0, stream>>>(h8, row_ptr, col_src, aggr, NN);
    gemm32<128, true, false, true><<<grid_g, blk, 0, stream>>>(
        aggr, hA, W2l_hi, W2r_hi, b2, hB, h8, nullptr);

    // Layer 3 (K=128, fused column-mean into gsum)
    aggregate128_fp8<<<grid_agg, blk, 0, stream>>>(h8, row_ptr, col_src, aggr, NN);
    gemm32<128, false, true, false><<<grid_g, blk, 0, stream>>>(
        aggr, hB, W3l_hi, W3r_hi, b3, nullptr, nullptr, gsum);

    // Heads (b3 folded into global mean here)
    heads_kernel<<<1, 256, 0, stream>>>(gsum, b3, Pw1, Pb1, Pw2, Pb2,
                                        Vw1, Vb1, Vw2, Vb2, outp,
                                        1.0f / (float)NN);
}